// Round 11
// baseline (377.218 us; speedup 1.0000x reference)
//
#include <hip/hip_runtime.h>
#include <cstdint>

typedef short bf8 __attribute__((ext_vector_type(8)));
typedef float f4 __attribute__((ext_vector_type(4)));

#define SEQ 2048
#define DIM 512
#define NMAT (512*512)
#define SCQ 0.04419417382415922f
#define LOG2E 1.4426950408889634f

__device__ inline unsigned short f2bf(float f){
    unsigned int u = __builtin_bit_cast(unsigned int, f);
    u = (u + 0x7FFFu + ((u >> 16) & 1u)) >> 16;
    return (unsigned short)u;
}

__device__ __forceinline__ float exp2fast(float x){
    return __builtin_amdgcn_exp2f(x);   // v_exp_f32 (base-2 native)
}

__device__ __forceinline__ void glds16(const unsigned short* gsrc, const unsigned short* ldst){
    __builtin_amdgcn_global_load_lds(
        (const __attribute__((address_space(1))) unsigned int*)gsrc,
        (__attribute__((address_space(3))) unsigned int*)ldst, 16, 0, 0);
}

// DPP butterfly reduce steps (VALU) replacing ds_bpermute shfl.
// 0xB1=xor1, 0x4E=xor2, 0x141=row_half_mirror (xor-4 equiv), 0x140=row_mirror (xor-8 equiv).
template<int CTRL>
__device__ __forceinline__ float dppadd(float x){
    const int t = __builtin_amdgcn_update_dpp(0, __builtin_bit_cast(int, x), CTRL, 0xF, 0xF, true);
    return x + __builtin_bit_cast(float, t);
}
template<int CTRL>
__device__ __forceinline__ float dppmax(float x){
    const int t = __builtin_amdgcn_update_dpp(0, __builtin_bit_cast(int, x), CTRL, 0xF, 0xF, true);
    return fmaxf(x, __builtin_bit_cast(float, t));
}

// ---------------- kernel 0: W (f32 [k][n]) -> Wt (bf16 [n][k]) ----------------
__global__ void prep_w(const float* __restrict__ Wv, const float* __restrict__ Wk,
                       const float* __restrict__ Wq, unsigned short* __restrict__ Wt)
{
    const int m = blockIdx.y;
    const float* W = (m == 0) ? Wv : ((m == 1) ? Wk : Wq);
    const int o = blockIdx.x * 256 + threadIdx.x;
    const int n = o >> 9;
    const int k = o & 511;
    Wt[m * NMAT + o] = f2bf(W[k * 512 + n]);
}

// ---------------- kernel 1: fused 3x GEMM (+LN / +transpose epilogue) ----------------
__global__ __launch_bounds__(512, 1) void gemm3(
    const float* __restrict__ vals, const float* __restrict__ keys, const float* __restrict__ ques,
    const unsigned short* __restrict__ Wt,
    const float* __restrict__ kg, const float* __restrict__ kbe,
    const float* __restrict__ qg, const float* __restrict__ qbe,
    unsigned short* __restrict__ vt, unsigned short* __restrict__ kbuf, unsigned short* __restrict__ qbuf)
{
    __shared__ unsigned short a_lds[64 * DIM];   // 64 KB, XOR-swizzled rows
    float* red1    = (float*)a_lds;
    float* red2    = red1 + 512;
    float* stat_mu = red2 + 512;
    float* stat_rs = stat_mu + 64;

    const int tid = threadIdx.x;
    const int wv  = tid >> 6;
    const int l   = tid & 63;
    const int g   = l >> 4;
    const int lr  = l & 15;
    const int gid = blockIdx.x;
    const int m   = gid >> 8;            // 0=v, 1=k, 2=q
    const int r0  = (gid & 255) * 64;
    const float* X = (m == 0) ? vals : ((m == 1) ? keys : ques);
    const unsigned short* W = Wt + m * NMAT;

    {
        const int row = tid >> 3;
        const int cb  = (tid & 7) * 4;
        const float* xr = X + (size_t)(r0 + row) * DIM;
        #pragma unroll
        for (int i = 0; i < 16; ++i){
            const int col = cb + i * 32;
            const float4 v = *reinterpret_cast<const float4*>(xr + col);
            ushort4 h;
            h.x = f2bf(v.x); h.y = f2bf(v.y); h.z = f2bf(v.z); h.w = f2bf(v.w);
            const int byte = ((row * DIM + col) * 2) ^ ((row & 7) << 4);
            *reinterpret_cast<ushort4*>(reinterpret_cast<char*>(a_lds) + byte) = h;
        }
    }
    __syncthreads();

    f4 acc[4][4];
    #pragma unroll
    for (int i = 0; i < 4; ++i)
        #pragma unroll
        for (int j = 0; j < 4; ++j)
            acc[i][j] = (f4){0.f, 0.f, 0.f, 0.f};

    const int nb = wv * 64;
    #pragma unroll 4
    for (int ks = 0; ks < 16; ++ks){
        const int kof = ks * 32 + g * 8;
        bf8 af[4], bfr[4];
        #pragma unroll
        for (int rt = 0; rt < 4; ++rt){
            const int row = 16 * rt + lr;
            const int byte = ((row * DIM + kof) * 2) ^ ((row & 7) << 4);
            af[rt] = *reinterpret_cast<const bf8*>(reinterpret_cast<const char*>(a_lds) + byte);
        }
        #pragma unroll
        for (int ct = 0; ct < 4; ++ct)
            bfr[ct] = *reinterpret_cast<const bf8*>(W + (size_t)(nb + 16 * ct + lr) * DIM + kof);
        #pragma unroll
        for (int rt = 0; rt < 4; ++rt)
            #pragma unroll
            for (int ct = 0; ct < 4; ++ct)
                acc[rt][ct] = __builtin_amdgcn_mfma_f32_16x16x32_bf16(af[rt], bfr[ct], acc[rt][ct], 0, 0, 0);
    }

    if (m == 0){
        __syncthreads();
        #pragma unroll
        for (int rt = 0; rt < 4; ++rt)
            #pragma unroll
            for (int r = 0; r < 4; ++r){
                const int row = 16 * rt + g * 4 + r;
                #pragma unroll
                for (int ct = 0; ct < 4; ++ct){
                    const int d = nb + 16 * ct + lr;
                    const int byte = (d * 128 + row * 2) ^ ((d & 7) << 4);
                    *reinterpret_cast<unsigned short*>(reinterpret_cast<char*>(a_lds) + byte) = f2bf(acc[rt][ct][r]);
                }
            }
        __syncthreads();
        const int bb = r0 >> 11;
        const int s0 = r0 & 2047;
        #pragma unroll
        for (int pq = 0; pq < 4; ++pq){
            const int d  = pq * 128 + (tid >> 2);
            const int sc = (tid & 3) * 16;
            const int base = d * 128 + sc * 2;
            const int sw = (d & 7) << 4;
            const bf8 x0 = *reinterpret_cast<const bf8*>(reinterpret_cast<const char*>(a_lds) + (base ^ sw));
            const bf8 x1 = *reinterpret_cast<const bf8*>(reinterpret_cast<const char*>(a_lds) + ((base + 16) ^ sw));
            unsigned short* dst = vt + (size_t)(bb * 512 + d) * SEQ + s0 + sc;
            *reinterpret_cast<bf8*>(dst)     = x0;
            *reinterpret_cast<bf8*>(dst + 8) = x1;
        }
        return;
    }

    const float* gamma = (m == 1) ? kg  : qg;
    const float* beta  = (m == 1) ? kbe : qbe;
    // q gets SCQ * log2(e): softmax runs in exp2 domain
    const float scale  = (m == 1) ? 1.0f : SCQ * LOG2E;
    unsigned short* outp = (m == 1) ? kbuf : qbuf;

    __syncthreads();
    #pragma unroll
    for (int rt = 0; rt < 4; ++rt){
        #pragma unroll
        for (int r = 0; r < 4; ++r){
            float s1 = 0.f, s2 = 0.f;
            #pragma unroll
            for (int ct = 0; ct < 4; ++ct){ const float v = acc[rt][ct][r]; s1 += v; s2 += v * v; }
            #pragma unroll
            for (int mm = 1; mm < 16; mm <<= 1){ s1 += __shfl_xor(s1, mm, 64); s2 += __shfl_xor(s2, mm, 64); }
            if (lr == 0){
                const int row = 16 * rt + g * 4 + r;
                red1[row * 8 + wv] = s1;
                red2[row * 8 + wv] = s2;
            }
        }
    }
    __syncthreads();
    if (tid < 64){
        float S1 = 0.f, S2 = 0.f;
        #pragma unroll
        for (int w = 0; w < 8; ++w){ S1 += red1[tid * 8 + w]; S2 += red2[tid * 8 + w]; }
        const float mu = S1 * (1.0f / 512.0f);
        const float var = S2 * (1.0f / 512.0f) - mu * mu;
        stat_mu[tid] = mu;
        stat_rs[tid] = rsqrtf(var + 1e-5f);
    }
    __syncthreads();
    #pragma unroll
    for (int rt = 0; rt < 4; ++rt){
        #pragma unroll
        for (int r = 0; r < 4; ++r){
            const int row = 16 * rt + g * 4 + r;
            const float mu = stat_mu[row];
            const float rs = stat_rs[row];
            #pragma unroll
            for (int ct = 0; ct < 4; ++ct){
                const int d = nb + 16 * ct + lr;
                const float v = ((acc[rt][ct][r] - mu) * rs * gamma[d] + beta[d]) * scale;
                outp[(size_t)(r0 + row) * DIM + d] = f2bf(v);
            }
        }
    }
}

// ---------------- kernel 2: flash attention, 16 waves + kh-split QK ----------------
// grid 256 = 8 batch * 32 p, block 1024 = 16 waves (4/SIMD; LDS 139 KB -> 1 block/CU).
// Round-10 failed on VGPR spill (qf[16]=64 too big for the 128/wave cap of a
// 16-wave block). Fix: QK waves (rt_=wv>>2, ct=wv&1, kh=(wv>>1)&1) compute a
// 16x16 S PARTIAL over K-half(256) -> qf[8]=32 VGPR. Partials in dual f32 S
// planes, summed in softmax (round-7 machinery). K ring-3 (96 KB), slot-explicit
// dummy staging. vmcnt: before QK = vmcnt(6) (drains K(2j+1)); b2 = vmcnt(2)
// (drains K(2j+2)+V, leaves K(2j+3) in flight).
__global__ __launch_bounds__(1024, 4) void attn(
    const unsigned short* __restrict__ qb, const unsigned short* __restrict__ kb,
    const unsigned short* __restrict__ vt, const float* __restrict__ qin,
    const float* __restrict__ g_o, const float* __restrict__ b_o,
    float* __restrict__ outp)
{
    __shared__ unsigned short k_lds[3 * 32 * DIM];   // 96 KB ring-3, swizzled content
    __shared__ float s2_lds[2][64][68];              // 34.8 KB dual S-partial planes
    __shared__ unsigned short p_lds[64 * 64];        // 8 KB: 128B rows, XOR swz
    __shared__ float l_lds[64], fac_lds[64];
    // epilogue reduction arrays alias s2_lds (dead after last softmax)
    float* red1    = &s2_lds[0][0][0];
    float* red2    = red1 + 1024;
    float* stat_mu = red2 + 1024;
    float* stat_rs = stat_mu + 64;

    const int tid = threadIdx.x;
    const int wv  = tid >> 6;             // 0..15
    const int l   = tid & 63;
    const int g   = l >> 4;
    const int lr  = l & 15;
    const int b   = blockIdx.x & 7;
    const int p   = blockIdx.x >> 3;      // 0..31
    const int q0a = 32 * p;               // rows 0..31  (light)
    const int q0b = 32 * (63 - p);        // rows 32..63 (heavy)
    const int n2  = (65 - p) >> 1;        // kv pairs (17..32)
    const int jL  = p >> 1;               // last pair with light rows active

    const int ct  = wv & 1;               // 16-col tile within 32-kv tile
    const int kh  = (wv >> 1) & 1;        // K-dim half (256)
    const int rt_ = wv >> 2;              // S row tile (16 rows), 0..3

    // Q fragments: rows 16*rt_+lr, K-half kh (qf[8] = 32 VGPR)
    bf8 qf[8];
    {
        const int row = 16 * rt_ + lr;
        const int qglob = (row < 32) ? (q0a + row) : (q0b + row - 32);
        const unsigned short* qr = qb + (size_t)(b * SEQ + qglob) * DIM + kh * 256 + g * 8;
        #pragma unroll
        for (int ks = 0; ks < 8; ++ks)
            qf[ks] = *reinterpret_cast<const bf8*>(qr + ks * 32);
    }

    // K staging: glds into explicit slot (rows 2wv, 2wv+1); dummies redirect
    // SOURCE to tile 0 but keep DEST = the free ring slot (round-7 fix).
    auto kglds = [&](int slot, int t){
        const int bo = slot * (32 * DIM);
        #pragma unroll
        for (int i = 0; i < 2; ++i){
            const int row = 2 * wv + i;
            glds16(kb + (size_t)(b * SEQ + t * 32 + row) * DIM + ((l * 8) ^ ((row & 7) * 8)),
                   k_lds + bo + row * DIM);
        }
    };

    kglds(0, 0);
    kglds(1, 1);

    // running softmax stats in REGISTERS (row = tid>>4 thread-stable; 16 copies/row)
    float m_reg = -__builtin_inff();
    float l_reg = 0.0f;

    f4 acc[4][2];
    #pragma unroll
    for (int rt = 0; rt < 4; ++rt)
        #pragma unroll
        for (int cv = 0; cv < 2; ++cv)
            acc[rt][cv] = (f4){0.f, 0.f, 0.f, 0.f};
    bf8 vst[4];   // V fragments: d = 32wv+16cv+lr, 64 kv cols

    // prologue drain: K(0), K(1), Q frags
    asm volatile("s_waitcnt vmcnt(0)" ::: "memory");
    __builtin_amdgcn_s_barrier();
    __builtin_amdgcn_sched_barrier(0);

    // PV helper: consumes p_lds/fac (pair jp) + vst (V of pair jp)
    auto do_pv = [&](int jp){
        const bool frozen = (jp > jL);
        __builtin_amdgcn_s_setprio(1);
        #pragma unroll
        for (int rt = 0; rt < 4; ++rt){
            if (rt < 2 && frozen) continue;    // light rows frozen
            float f[4];
            #pragma unroll
            for (int r = 0; r < 4; ++r) f[r] = fac_lds[16 * rt + 4 * g + r];
            #pragma unroll
            for (int cv = 0; cv < 2; ++cv)
                #pragma unroll
                for (int r = 0; r < 4; ++r)
                    acc[rt][cv][r] *= f[r];
            const int prow = 16 * rt + lr;
            const int sw = (prow & 7) << 4;
            const bf8 pa0 = *reinterpret_cast<const bf8*>(
                reinterpret_cast<const char*>(p_lds) + prow * 128 + ((g * 16) ^ sw));
            const bf8 pa1 = *reinterpret_cast<const bf8*>(
                reinterpret_cast<const char*>(p_lds) + prow * 128 + ((64 + g * 16) ^ sw));
            #pragma unroll
            for (int cv = 0; cv < 2; ++cv){
                acc[rt][cv] = __builtin_amdgcn_mfma_f32_16x16x32_bf16(pa0, vst[2 * cv],     acc[rt][cv], 0, 0, 0);
                acc[rt][cv] = __builtin_amdgcn_mfma_f32_16x16x32_bf16(pa1, vst[2 * cv + 1], acc[rt][cv], 0, 0, 0);
            }
        }
        __builtin_amdgcn_s_setprio(0);
    };

    for (int j = 0; j < n2; ++j){
        const int k0 = 64 * j;
        const int tp = 2 * j + 2;

        // ===== phase 1: stage slot tp%3, PV(j-1), V(j) loads, QK(j) =====
        kglds(tp % 3, tp < 2 * n2 ? tp : 0);

        if (j > 0) do_pv(j - 1);

        #pragma unroll
        for (int cv = 0; cv < 2; ++cv)
            #pragma unroll
            for (int ks = 0; ks < 2; ++ks)
                vst[2 * cv + ks] = *reinterpret_cast<const bf8*>(
                    vt + (size_t)(b * DIM + 32 * wv + 16 * cv + lr) * SEQ + k0 + 32 * ks + g * 8);

        // outstanding: [2x K(2j+1) (oldest), 2x phase-1 glds, 4x V] = 8
        // -> drain exactly the 2 oldest (tile 2j+1, needed by QK h=1)
        asm volatile("s_waitcnt vmcnt(6)" ::: "memory");

        if (rt_ >= 2 || j <= jL){
            const int krow  = 16 * ct + lr;
            const int rbase = krow * 1024;
            const int rx    = (krow & 7) << 4;
            const int dbase = kh * 512;
            __builtin_amdgcn_s_setprio(1);
            #pragma unroll
            for (int h = 0; h < 2; ++h){
                const char* kbuf = reinterpret_cast<const char*>(k_lds) + ((2 * j + h) % 3) * 32768;
                f4 sa[2];
                sa[0] = (f4){0.f,0.f,0.f,0.f}; sa[1] = (f4){0.f,0.f,0.f,0.f};
                #pragma unroll
                for (int ks = 0; ks < 8; ++ks){
                    const bf8 bk = *reinterpret_cast<const bf8*>(
                        kbuf + rbase + ((dbase + ks * 64 + g * 16) ^ rx));
                    sa[ks & 1] = __builtin_amdgcn_mfma_f32_16x16x32_bf16(qf[ks], bk, sa[ks & 1], 0, 0, 0);
                }
                const f4 s = sa[0] + sa[1];
                const int srow = 16 * rt_ + 4 * g;
                #pragma unroll
                for (int r = 0; r < 4; ++r)
                    s2_lds[kh][srow + r][32 * h + 16 * ct + lr] = s[r];
            }
            __builtin_amdgcn_s_setprio(0);
        }
        // b1: S partials visible; NO vmem drain
        asm volatile("s_waitcnt lgkmcnt(0)" ::: "memory");
        __builtin_amdgcn_s_barrier();
        __builtin_amdgcn_sched_barrier(0);

        // ===== phase 2: stage slot (tp+1)%3 (free after b1), softmax(j) =====
        kglds((tp + 1) % 3, tp + 1 < 2 * n2 ? tp + 1 : 0);

        {
            const int row = tid >> 4;
            const int cp  = tid & 15;
            if (row >= 32 || j <= jL){
                const float4 x0 = *reinterpret_cast<const float4*>(&s2_lds[0][row][4 * cp]);
                const float4 y0 = *reinterpret_cast<const float4*>(&s2_lds[1][row][4 * cp]);
                float av[4] = {x0.x + y0.x, x0.y + y0.y, x0.z + y0.z, x0.w + y0.w};
                const int qrow = (row < 32) ? (q0a + row) : (q0b + row - 32);
                const int kc = k0 + 4 * cp;
                #pragma unroll
                for (int jj = 0; jj < 4; ++jj)
                    if (kc + jj > qrow) av[jj] = -1e30f;
                float pm = fmaxf(fmaxf(av[0], av[1]), fmaxf(av[2], av[3]));
                pm = dppmax<0xB1>(pm); pm = dppmax<0x4E>(pm);
                pm = dppmax<0x141>(pm); pm = dppmax<0x140>(pm);
                const float mo = m_reg;
                const float mn = fmaxf(mo, pm);
                float e[4];
                #pragma unroll
                for (int jj = 0; jj < 4; ++jj) e[jj] = exp2fast(av[jj] - mn);
                float ts = (e[0] + e[1]) + (e[2] + e[3]);
                ts = dppadd<0xB1>(ts); ts = dppadd<0x4E>(ts);
                ts = dppadd<0x141>(ts); ts = dppadd<0x140>(ts);
                const float fc = exp2fast(mo - mn);
                m_reg = mn;
                l_reg = l_reg * fc + ts;
                if (cp == 0) fac_lds[row] = fc;
                uint2 pk;
                pk.x = (unsigned int)f2bf(e[0]) | ((unsigned int)f2bf(e[1]) << 16);
                pk.y = (unsigned int)f2bf(e[2]) | ((unsigned int)f2bf(e[3]) << 16);
                *reinterpret_cast<uint2*>(reinterpret_cast<char*>(p_lds) +
                    row * 128 + ((cp * 8) ^ ((row & 7) << 4))) = pk;
            }
        }
        // b2: P/fac visible; vmcnt(2) drains phase-1 K + V(j), leaves phase-2 K in flight
        asm volatile("s_waitcnt vmcnt(2)" ::: "memory");
        asm volatile("s_waitcnt lgkmcnt(0)" ::: "memory");
        __builtin_amdgcn_s_barrier();
        __builtin_amdgcn_sched_barrier(0);
    }

    // publish register l to LDS for the epilogue's (different) thread mapping
    if ((tid & 15) == 0) l_lds[tid >> 4] = l_reg;

    // final PV (softmax/V of pair n2-1; V drained at last b2)
    asm volatile("s_waitcnt vmcnt(0)" ::: "memory");
    do_pv(n2 - 1);
    __syncthreads();   // l_lds visible to all

    // ---- finalize: /l, +residual, LN, store (64 rows x 512 d, d = 32wv+16cv+lr) ----
    float li[4][4];
    #pragma unroll
    for (int rt = 0; rt < 4; ++rt)
        #pragma unroll
        for (int r = 0; r < 4; ++r)
            li[rt][r] = 1.0f / l_lds[16 * rt + 4 * g + r];
    #pragma unroll
    for (int rt = 0; rt < 4; ++rt){
        #pragma unroll
        for (int cv = 0; cv < 2; ++cv){
            #pragma unroll
            for (int r = 0; r < 4; ++r){
                const int row = 16 * rt + 4 * g + r;
                const int qglob = (row < 32) ? (q0a + row) : (q0b + row - 32);
                const int d = 32 * wv + 16 * cv + lr;
                acc[rt][cv][r] = acc[rt][cv][r] * li[rt][r]
                               + qin[(size_t)(b * SEQ + qglob) * DIM + d];
            }
        }
    }
    __syncthreads();   // s2_lds reads fully done (aliased by red1/red2 below)
    #pragma unroll
    for (int rt = 0; rt < 4; ++rt){
        #pragma unroll
        for (int r = 0; r < 4; ++r){
            float s1 = 0.f, s2 = 0.f;
            #pragma unroll
            for (int cv = 0; cv < 2; ++cv){ const float v = acc[rt][cv][r]; s1 += v; s2 += v * v; }
            s1 = dppadd<0xB1>(s1); s1 = dppadd<0x4E>(s1); s1 = dppadd<0x141>(s1); s1 = dppadd<0x140>(s1);
            s2 = dppadd<0xB1>(s2); s2 = dppadd<0x4E>(s2); s2 = dppadd<0x141>(s2); s2 = dppadd<0x140>(s2);
            if (lr == 0){
                const int row = 16 * rt + 4 * g + r;
                red1[row * 16 + wv] = s1;
                red2[row * 16 + wv] = s2;
            }
        }
    }
    __syncthreads();
    if (tid < 64){
        float S1 = 0.f, S2 = 0.f;
        #pragma unroll
        for (int w = 0; w < 16; ++w){ S1 += red1[tid * 16 + w]; S2 += red2[tid * 16 + w]; }
        const float mu = S1 * (1.0f / 512.0f);
        const float var = S2 * (1.0f / 512.0f) - mu * mu;
        stat_mu[tid] = mu;
        stat_rs[tid] = rsqrtf(var + 1e-5f);
    }
    __syncthreads();
    #pragma unroll
    for (int rt = 0; rt < 4; ++rt){
        #pragma unroll
        for (int r = 0; r < 4; ++r){
            const int row = 16 * rt + 4 * g + r;
            const int qglob = (row < 32) ? (q0a + row) : (q0b + row - 32);
            const float mu = stat_mu[row];
            const float rs = stat_rs[row];
            #pragma unroll
            for (int cv = 0; cv < 2; ++cv){
                const int d = 32 * wv + 16 * cv + lr;
                outp[(size_t)(b * SEQ + qglob) * DIM + d] =
                    (acc[rt][cv][r] - mu) * rs * g_o[d] + b_o[d];
            }
        }
    }
}

extern "C" void kernel_launch(void* const* d_in, const int* in_sizes, int n_in,
                              void* d_out, int out_size, void* d_ws, size_t ws_size,
                              hipStream_t stream)
{
    (void)in_sizes; (void)n_in; (void)out_size; (void)ws_size;
    const float* vals = (const float*)d_in[0];
    const float* keys = (const float*)d_in[1];
    const float* ques = (const float*)d_in[2];
    const float* Wv   = (const float*)d_in[5];
    const float* Wk   = (const float*)d_in[6];
    const float* Wq   = (const float*)d_in[7];
    const float* ln_k_g = (const float*)d_in[8];
    const float* ln_k_b = (const float*)d_in[9];
    const float* ln_q_g = (const float*)d_in[10];
    const float* ln_q_b = (const float*)d_in[11];
    const float* ln_o_g = (const float*)d_in[12];
    const float* ln_o_b = (const float*)d_in[13];
    float* outp = (float*)d_out;

    char* ws = (char*)d_ws;
    unsigned short* qbuf = (unsigned short*)(ws);
    unsigned short* kbuf = (unsigned short*)(ws + (size_t)16 * 1024 * 1024);
    unsigned short* vt   = (unsigned short*)(ws + (size_t)32 * 1024 * 1024);
    unsigned short* Wt   = (unsigned short*)(ws + (size_t)48 * 1024 * 1024);

    prep_w<<<dim3(1024, 3), 256, 0, stream>>>(Wv, Wk, Wq, Wt);

    gemm3<<<768, 512, 0, stream>>>(vals, keys, ques, Wt,
                                   ln_k_g, ln_k_b, ln_q_g, ln_q_b,
                                   vt, kbuf, qbuf);

    attn<<<256, 1024, 0, stream>>>(qbuf, kbuf, vt, ques, ln_o_g, ln_o_b, outp);
}

// Round 12
// 238.038 us; speedup vs baseline: 1.5847x; 1.5847x over previous
//
#include <hip/hip_runtime.h>
#include <cstdint>

typedef short bf8 __attribute__((ext_vector_type(8)));
typedef float f4 __attribute__((ext_vector_type(4)));

#define SEQ 2048
#define DIM 512
#define NMAT (512*512)
#define SCQ 0.04419417382415922f
#define LOG2E 1.4426950408889634f

__device__ inline unsigned short f2bf(float f){
    unsigned int u = __builtin_bit_cast(unsigned int, f);
    u = (u + 0x7FFFu + ((u >> 16) & 1u)) >> 16;
    return (unsigned short)u;
}

__device__ __forceinline__ float exp2fast(float x){
    return __builtin_amdgcn_exp2f(x);   // v_exp_f32 (base-2 native)
}

__device__ __forceinline__ void glds16(const unsigned short* gsrc, const unsigned short* ldst){
    __builtin_amdgcn_global_load_lds(
        (const __attribute__((address_space(1))) unsigned int*)gsrc,
        (__attribute__((address_space(3))) unsigned int*)ldst, 16, 0, 0);
}

// DPP butterfly reduce steps (VALU). 0xB1=xor1, 0x4E=xor2,
// 0x141=row_half_mirror (xor4-equiv), 0x140=row_mirror (xor8-equiv).
template<int CTRL>
__device__ __forceinline__ float dppadd(float x){
    const int t = __builtin_amdgcn_update_dpp(0, __builtin_bit_cast(int, x), CTRL, 0xF, 0xF, true);
    return x + __builtin_bit_cast(float, t);
}
template<int CTRL>
__device__ __forceinline__ float dppmax(float x){
    const int t = __builtin_amdgcn_update_dpp(0, __builtin_bit_cast(int, x), CTRL, 0xF, 0xF, true);
    return fmaxf(x, __builtin_bit_cast(float, t));
}

// ---------------- kernel 0: W (f32 [k][n]) -> Wt (bf16 [n][k]) ----------------
__global__ void prep_w(const float* __restrict__ Wv, const float* __restrict__ Wk,
                       const float* __restrict__ Wq, unsigned short* __restrict__ Wt)
{
    const int m = blockIdx.y;
    const float* W = (m == 0) ? Wv : ((m == 1) ? Wk : Wq);
    const int o = blockIdx.x * 256 + threadIdx.x;
    const int n = o >> 9;
    const int k = o & 511;
    Wt[m * NMAT + o] = f2bf(W[k * 512 + n]);
}

// ---------------- kernel 1: fused 3x GEMM (+LN / +transpose epilogue) ----------------
__global__ __launch_bounds__(512, 1) void gemm3(
    const float* __restrict__ vals, const float* __restrict__ keys, const float* __restrict__ ques,
    const unsigned short* __restrict__ Wt,
    const float* __restrict__ kg, const float* __restrict__ kbe,
    const float* __restrict__ qg, const float* __restrict__ qbe,
    unsigned short* __restrict__ vt, unsigned short* __restrict__ kbuf, unsigned short* __restrict__ qbuf)
{
    __shared__ unsigned short a_lds[64 * DIM];   // 64 KB, XOR-swizzled rows
    float* red1    = (float*)a_lds;
    float* red2    = red1 + 512;
    float* stat_mu = red2 + 512;
    float* stat_rs = stat_mu + 64;

    const int tid = threadIdx.x;
    const int wv  = tid >> 6;
    const int l   = tid & 63;
    const int g   = l >> 4;
    const int lr  = l & 15;
    const int gid = blockIdx.x;
    const int m   = gid >> 8;            // 0=v, 1=k, 2=q
    const int r0  = (gid & 255) * 64;
    const float* X = (m == 0) ? vals : ((m == 1) ? keys : ques);
    const unsigned short* W = Wt + m * NMAT;

    {
        const int row = tid >> 3;
        const int cb  = (tid & 7) * 4;
        const float* xr = X + (size_t)(r0 + row) * DIM;
        #pragma unroll
        for (int i = 0; i < 16; ++i){
            const int col = cb + i * 32;
            const float4 v = *reinterpret_cast<const float4*>(xr + col);
            ushort4 h;
            h.x = f2bf(v.x); h.y = f2bf(v.y); h.z = f2bf(v.z); h.w = f2bf(v.w);
            const int byte = ((row * DIM + col) * 2) ^ ((row & 7) << 4);
            *reinterpret_cast<ushort4*>(reinterpret_cast<char*>(a_lds) + byte) = h;
        }
    }
    __syncthreads();

    f4 acc[4][4];
    #pragma unroll
    for (int i = 0; i < 4; ++i)
        #pragma unroll
        for (int j = 0; j < 4; ++j)
            acc[i][j] = (f4){0.f, 0.f, 0.f, 0.f};

    const int nb = wv * 64;
    #pragma unroll 4
    for (int ks = 0; ks < 16; ++ks){
        const int kof = ks * 32 + g * 8;
        bf8 af[4], bfr[4];
        #pragma unroll
        for (int rt = 0; rt < 4; ++rt){
            const int row = 16 * rt + lr;
            const int byte = ((row * DIM + kof) * 2) ^ ((row & 7) << 4);
            af[rt] = *reinterpret_cast<const bf8*>(reinterpret_cast<const char*>(a_lds) + byte);
        }
        #pragma unroll
        for (int ct = 0; ct < 4; ++ct)
            bfr[ct] = *reinterpret_cast<const bf8*>(W + (size_t)(nb + 16 * ct + lr) * DIM + kof);
        #pragma unroll
        for (int rt = 0; rt < 4; ++rt)
            #pragma unroll
            for (int ct = 0; ct < 4; ++ct)
                acc[rt][ct] = __builtin_amdgcn_mfma_f32_16x16x32_bf16(af[rt], bfr[ct], acc[rt][ct], 0, 0, 0);
    }

    if (m == 0){
        __syncthreads();
        #pragma unroll
        for (int rt = 0; rt < 4; ++rt)
            #pragma unroll
            for (int r = 0; r < 4; ++r){
                const int row = 16 * rt + g * 4 + r;
                #pragma unroll
                for (int ct = 0; ct < 4; ++ct){
                    const int d = nb + 16 * ct + lr;
                    const int byte = (d * 128 + row * 2) ^ ((d & 7) << 4);
                    *reinterpret_cast<unsigned short*>(reinterpret_cast<char*>(a_lds) + byte) = f2bf(acc[rt][ct][r]);
                }
            }
        __syncthreads();
        const int bb = r0 >> 11;
        const int s0 = r0 & 2047;
        #pragma unroll
        for (int pq = 0; pq < 4; ++pq){
            const int d  = pq * 128 + (tid >> 2);
            const int sc = (tid & 3) * 16;
            const int base = d * 128 + sc * 2;
            const int sw = (d & 7) << 4;
            const bf8 x0 = *reinterpret_cast<const bf8*>(reinterpret_cast<const char*>(a_lds) + (base ^ sw));
            const bf8 x1 = *reinterpret_cast<const bf8*>(reinterpret_cast<const char*>(a_lds) + ((base + 16) ^ sw));
            unsigned short* dst = vt + (size_t)(bb * 512 + d) * SEQ + s0 + sc;
            *reinterpret_cast<bf8*>(dst)     = x0;
            *reinterpret_cast<bf8*>(dst + 8) = x1;
        }
        return;
    }

    const float* gamma = (m == 1) ? kg  : qg;
    const float* beta  = (m == 1) ? kbe : qbe;
    // q gets SCQ * log2(e): softmax runs in exp2 domain
    const float scale  = (m == 1) ? 1.0f : SCQ * LOG2E;
    unsigned short* outp = (m == 1) ? kbuf : qbuf;

    __syncthreads();
    #pragma unroll
    for (int rt = 0; rt < 4; ++rt){
        #pragma unroll
        for (int r = 0; r < 4; ++r){
            float s1 = 0.f, s2 = 0.f;
            #pragma unroll
            for (int ct = 0; ct < 4; ++ct){ const float v = acc[rt][ct][r]; s1 += v; s2 += v * v; }
            #pragma unroll
            for (int mm = 1; mm < 16; mm <<= 1){ s1 += __shfl_xor(s1, mm, 64); s2 += __shfl_xor(s2, mm, 64); }
            if (lr == 0){
                const int row = 16 * rt + g * 4 + r;
                red1[row * 8 + wv] = s1;
                red2[row * 8 + wv] = s2;
            }
        }
    }
    __syncthreads();
    if (tid < 64){
        float S1 = 0.f, S2 = 0.f;
        #pragma unroll
        for (int w = 0; w < 8; ++w){ S1 += red1[tid * 8 + w]; S2 += red2[tid * 8 + w]; }
        const float mu = S1 * (1.0f / 512.0f);
        const float var = S2 * (1.0f / 512.0f) - mu * mu;
        stat_mu[tid] = mu;
        stat_rs[tid] = rsqrtf(var + 1e-5f);
    }
    __syncthreads();
    #pragma unroll
    for (int rt = 0; rt < 4; ++rt){
        #pragma unroll
        for (int r = 0; r < 4; ++r){
            const int row = 16 * rt + g * 4 + r;
            const float mu = stat_mu[row];
            const float rs = stat_rs[row];
            #pragma unroll
            for (int ct = 0; ct < 4; ++ct){
                const int d = nb + 16 * ct + lr;
                const float v = ((acc[rt][ct][r] - mu) * rs * gamma[d] + beta[d]) * scale;
                outp[(size_t)(r0 + row) * DIM + d] = f2bf(v);
            }
        }
    }
}

// ---------------- kernel 2: flash attention, producer/consumer wave split ----------------
// grid 256 = 8 batch * 32 p, 512 thr = 8 waves (2/SIMD: 1 producer + 1 consumer per SIMD).
// Rows 0-31 = qt=p (light), rows 32-63 = qt=63-p. KB=32 kv per phase, n = 64-p tiles.
// Pipeline depth 3, ONE barrier/phase, phases run CONCURRENTLY on different waves:
//   phase i: producers (wv<4, rows 16wv): QK(i) -> s_dbuf[i&1]
//            consumers (wv>=4, d-slice 128(wv-4)): PV(i-2) [p_dbuf/fac (i-2)&1, V from L2]
//                                                  + softmax(i-1) [s_dbuf (i-1)&1 -> p/fac (i-1)&1]
// K ring-3 (96 KB) staged by all waves at phase top, vmcnt(0) drain at phase end
// (full phase to land). Each role has its OWN loop so qf (producer) and acc
// (consumer, 128 VGPR) liveness don't overlap -> no spill at 2 waves/SIMD.
__global__ __launch_bounds__(512, 2) void attn(
    const unsigned short* __restrict__ qb, const unsigned short* __restrict__ kb,
    const unsigned short* __restrict__ vt, const float* __restrict__ qin,
    const float* __restrict__ g_o, const float* __restrict__ b_o,
    float* __restrict__ outp)
{
    __shared__ unsigned short k_lds[3 * 32 * DIM];   // 96 KB ring-3, swizzled content
    __shared__ float s_dbuf[2][64][36];              // 18 KB S double-buffer (32 kv + pad)
    __shared__ unsigned short p_dbuf[2][64 * 40];    // 10 KB P dbuf: 80B rows (16B-aligned)
    __shared__ float fac_dbuf[2][64];
    __shared__ float l_lds[64];
    // epilogue arrays alias s_dbuf (dead after last softmax)
    float* red1    = &s_dbuf[0][0][0];               // [64][4]
    float* red2    = red1 + 256;
    float* stat_mu = red2 + 256;
    float* stat_rs = stat_mu + 64;

    const int tid = threadIdx.x;
    const int wv  = tid >> 6;
    const int l   = tid & 63;
    const int g   = l >> 4;
    const int lr  = l & 15;
    const int b   = blockIdx.x & 7;
    const int p   = blockIdx.x >> 3;      // 0..31
    const int q0a = 32 * p;               // rows 0..31  (light)
    const int q0b = 32 * (63 - p);        // rows 32..63 (heavy)
    const int n   = 64 - p;               // 32-kv tiles (33..64)

    // K staging: glds into explicit ring slot, linear dest + inverse-swizzled src
    auto kglds = [&](int slot, int t){
        const int bo = slot * (32 * DIM);
        #pragma unroll
        for (int i2 = 0; i2 < 4; ++i2){
            const int row = 4 * wv + i2;
            glds16(kb + (size_t)(b * SEQ + t * 32 + row) * DIM + ((l * 8) ^ ((row & 7) * 8)),
                   k_lds + bo + row * DIM);
        }
    };

    kglds(0, 0);
    kglds(1, 1);
    asm volatile("s_waitcnt vmcnt(0)" ::: "memory");
    __builtin_amdgcn_s_barrier();
    __builtin_amdgcn_sched_barrier(0);

    if (wv < 4){
        // ======================= PRODUCER: QK(i) =======================
        bf8 qf[16];   // rows 16wv+lr, full K=512
        {
            const int row = 16 * wv + lr;
            const int qglob = (row < 32) ? (q0a + row) : (q0b + row - 32);
            const unsigned short* qr = qb + (size_t)(b * SEQ + qglob) * DIM + g * 8;
            #pragma unroll
            for (int ks = 0; ks < 16; ++ks)
                qf[ks] = *reinterpret_cast<const bf8*>(qr + ks * 32);
        }
        for (int i = 0; i < n + 2; ++i){
            if (i + 2 < n) kglds((i + 2) % 3, i + 2);
            if (i < n && (wv >= 2 || i <= p)){      // light producers frozen past tile p
                const char* kbuf = reinterpret_cast<const char*>(k_lds) + (i % 3) * 32768;
                __builtin_amdgcn_s_setprio(1);
                #pragma unroll
                for (int ct = 0; ct < 2; ++ct){
                    const int krow  = 16 * ct + lr;
                    const int rbase = krow * 1024;
                    const int rx    = (krow & 7) << 4;
                    f4 sa[4];
                    sa[0] = (f4){0.f,0.f,0.f,0.f}; sa[1] = (f4){0.f,0.f,0.f,0.f};
                    sa[2] = (f4){0.f,0.f,0.f,0.f}; sa[3] = (f4){0.f,0.f,0.f,0.f};
                    #pragma unroll
                    for (int ks = 0; ks < 16; ++ks){
                        const bf8 bk = *reinterpret_cast<const bf8*>(
                            kbuf + rbase + ((ks * 64 + g * 16) ^ rx));
                        sa[ks & 3] = __builtin_amdgcn_mfma_f32_16x16x32_bf16(qf[ks], bk, sa[ks & 3], 0, 0, 0);
                    }
                    const f4 s = (sa[0] + sa[1]) + (sa[2] + sa[3]);
                    const int srow = 16 * wv + 4 * g;
                    #pragma unroll
                    for (int r = 0; r < 4; ++r)
                        s_dbuf[i & 1][srow + r][16 * ct + lr] = s[r];
                }
                __builtin_amdgcn_s_setprio(0);
            }
            asm volatile("s_waitcnt vmcnt(0)" ::: "memory");
            asm volatile("s_waitcnt lgkmcnt(0)" ::: "memory");
            __builtin_amdgcn_s_barrier();
            __builtin_amdgcn_sched_barrier(0);
        }
        // epilogue participation (3 barriers; stats computed by tid<64 = producer wave 0)
        __builtin_amdgcn_s_barrier();                 // (1) l_lds visible
        __builtin_amdgcn_s_barrier();                 // (2) red written
        if (tid < 64){
            float S1 = 0.f, S2 = 0.f;
            #pragma unroll
            for (int w = 0; w < 4; ++w){ S1 += red1[tid * 4 + w]; S2 += red2[tid * 4 + w]; }
            const float mu = S1 * (1.0f / 512.0f);
            const float var = S2 * (1.0f / 512.0f) - mu * mu;
            stat_mu[tid] = mu;
            stat_rs[tid] = rsqrtf(var + 1e-5f);
        }
        asm volatile("s_waitcnt lgkmcnt(0)" ::: "memory");
        __builtin_amdgcn_s_barrier();                 // (3) stats visible
    } else {
        // ================= CONSUMER: PV(i-2) + softmax(i-1) =================
        const int c   = wv - 4;           // d-slice 128c..128c+127
        const int q   = tid - 256;        // 0..255
        const int row = q >> 2;           // softmax row 0..63 (4 threads/row)
        const int cp  = q & 3;            // 8 kv cols each
        float m_reg = -__builtin_inff();
        float l_reg = 0.0f;
        f4 acc[4][8];                     // [q-tile][d-tile]: 128 VGPR
        #pragma unroll
        for (int rt = 0; rt < 4; ++rt)
            #pragma unroll
            for (int dt = 0; dt < 8; ++dt)
                acc[rt][dt] = (f4){0.f, 0.f, 0.f, 0.f};

        for (int i = 0; i < n + 2; ++i){
            if (i + 2 < n) kglds((i + 2) % 3, i + 2);

            if (i >= 2){
                const int k0 = 32 * (i - 2);
                const bool frozen = (i - 2) > p;
                bf8 vst[8];
                #pragma unroll
                for (int dt = 0; dt < 8; ++dt)
                    vst[dt] = *reinterpret_cast<const bf8*>(
                        vt + (size_t)(b * DIM + 128 * c + 16 * dt + lr) * SEQ + k0 + g * 8);
                const float* fac = fac_dbuf[(i - 2) & 1];
                const char* pb = reinterpret_cast<const char*>(p_dbuf[(i - 2) & 1]);
                bf8 pa[4];
                #pragma unroll
                for (int rt = 0; rt < 4; ++rt){
                    if (rt < 2 && frozen) continue;   // light rows frozen
                    float f0 = fac[16 * rt + 4 * g + 0];
                    float f1 = fac[16 * rt + 4 * g + 1];
                    float f2 = fac[16 * rt + 4 * g + 2];
                    float f3 = fac[16 * rt + 4 * g + 3];
                    pa[rt] = *reinterpret_cast<const bf8*>(pb + (16 * rt + lr) * 80 + g * 16);
                    #pragma unroll
                    for (int dt = 0; dt < 8; ++dt){
                        acc[rt][dt][0] *= f0; acc[rt][dt][1] *= f1;
                        acc[rt][dt][2] *= f2; acc[rt][dt][3] *= f3;
                    }
                }
                asm volatile("s_waitcnt vmcnt(0)" ::: "memory");   // V landed (K glds too)
                __builtin_amdgcn_sched_barrier(0);
                __builtin_amdgcn_s_setprio(1);
                #pragma unroll
                for (int rt = 0; rt < 4; ++rt){
                    if (rt < 2 && frozen) continue;
                    #pragma unroll
                    for (int dt = 0; dt < 8; ++dt)
                        acc[rt][dt] = __builtin_amdgcn_mfma_f32_16x16x32_bf16(pa[rt], vst[dt], acc[rt][dt], 0, 0, 0);
                }
                __builtin_amdgcn_s_setprio(0);
            }

            if (i >= 1 && i - 1 < n){
                const int t = i - 1;
                if (row >= 32 || t <= p){
                    const float4 x0 = *reinterpret_cast<const float4*>(&s_dbuf[t & 1][row][8 * cp]);
                    const float4 x1 = *reinterpret_cast<const float4*>(&s_dbuf[t & 1][row][8 * cp + 4]);
                    float av[8] = {x0.x, x0.y, x0.z, x0.w, x1.x, x1.y, x1.z, x1.w};
                    const int qrow = (row < 32) ? (q0a + row) : (q0b + row - 32);
                    const int kc = 32 * t + 8 * cp;
                    #pragma unroll
                    for (int jj = 0; jj < 8; ++jj)
                        if (kc + jj > qrow) av[jj] = -1e30f;
                    float pm = fmaxf(fmaxf(fmaxf(av[0], av[1]), fmaxf(av[2], av[3])),
                                     fmaxf(fmaxf(av[4], av[5]), fmaxf(av[6], av[7])));
                    pm = dppmax<0xB1>(pm); pm = dppmax<0x4E>(pm);   // 4 threads/row
                    const float mo = m_reg;
                    const float mn = fmaxf(mo, pm);
                    float e[8];
                    #pragma unroll
                    for (int jj = 0; jj < 8; ++jj) e[jj] = exp2fast(av[jj] - mn);
                    float ts = ((e[0] + e[1]) + (e[2] + e[3])) + ((e[4] + e[5]) + (e[6] + e[7]));
                    ts = dppadd<0xB1>(ts); ts = dppadd<0x4E>(ts);
                    const float fc = exp2fast(mo - mn);
                    m_reg = mn;
                    l_reg = l_reg * fc + ts;
                    if (cp == 0) fac_dbuf[t & 1][row] = fc;
                    uint4 pk;
                    pk.x = (unsigned int)f2bf(e[0]) | ((unsigned int)f2bf(e[1]) << 16);
                    pk.y = (unsigned int)f2bf(e[2]) | ((unsigned int)f2bf(e[3]) << 16);
                    pk.z = (unsigned int)f2bf(e[4]) | ((unsigned int)f2bf(e[5]) << 16);
                    pk.w = (unsigned int)f2bf(e[6]) | ((unsigned int)f2bf(e[7]) << 16);
                    *reinterpret_cast<uint4*>(reinterpret_cast<char*>(p_dbuf[t & 1]) +
                        row * 80 + cp * 16) = pk;
                }
            }
            asm volatile("s_waitcnt vmcnt(0)" ::: "memory");
            asm volatile("s_waitcnt lgkmcnt(0)" ::: "memory");
            __builtin_amdgcn_s_barrier();
            __builtin_amdgcn_sched_barrier(0);
        }

        // ---- epilogue: /l, +residual, LN partials, store ----
        if (cp == 0) l_lds[row] = l_reg;
        asm volatile("s_waitcnt lgkmcnt(0)" ::: "memory");
        __builtin_amdgcn_s_barrier();                 // (1)
        float li[4][4];
        #pragma unroll
        for (int rt = 0; rt < 4; ++rt)
            #pragma unroll
            for (int r = 0; r < 4; ++r)
                li[rt][r] = 1.0f / l_lds[16 * rt + 4 * g + r];
        #pragma unroll
        for (int rt = 0; rt < 4; ++rt){
            #pragma unroll
            for (int dt = 0; dt < 8; ++dt){
                #pragma unroll
                for (int r = 0; r < 4; ++r){
                    const int rw = 16 * rt + 4 * g + r;
                    const int qglob = (rw < 32) ? (q0a + rw) : (q0b + rw - 32);
                    const int d = 128 * c + 16 * dt + lr;
                    acc[rt][dt][r] = acc[rt][dt][r] * li[rt][r]
                                   + qin[(size_t)(b * SEQ + qglob) * DIM + d];
                }
            }
        }
        #pragma unroll
        for (int rt = 0; rt < 4; ++rt){
            #pragma unroll
            for (int r = 0; r < 4; ++r){
                float s1 = 0.f, s2 = 0.f;
                #pragma unroll
                for (int dt = 0; dt < 8; ++dt){ const float v = acc[rt][dt][r]; s1 += v; s2 += v * v; }
                s1 = dppadd<0xB1>(s1); s1 = dppadd<0x4E>(s1); s1 = dppadd<0x141>(s1); s1 = dppadd<0x140>(s1);
                s2 = dppadd<0xB1>(s2); s2 = dppadd<0x4E>(s2); s2 = dppadd<0x141>(s2); s2 = dppadd<0x140>(s2);
                if (lr == 0){
                    const int rw = 16 * rt + 4 * g + r;
                    red1[rw * 4 + c] = s1;
                    red2[rw * 4 + c] = s2;
                }
            }
        }
        asm volatile("s_waitcnt lgkmcnt(0)" ::: "memory");
        __builtin_amdgcn_s_barrier();                 // (2)
        __builtin_amdgcn_s_barrier();                 // (3) stats (by producer wave 0) visible
        #pragma unroll
        for (int rt = 0; rt < 4; ++rt){
            #pragma unroll
            for (int r = 0; r < 4; ++r){
                const int rw = 16 * rt + 4 * g + r;
                const int qglob = (rw < 32) ? (q0a + rw) : (q0b + rw - 32);
                const float mu = stat_mu[rw];
                const float rs = stat_rs[rw];
                #pragma unroll
                for (int dt = 0; dt < 8; ++dt){
                    const int d = 128 * c + 16 * dt + lr;
                    outp[(size_t)(b * SEQ + qglob) * DIM + d] =
                        (acc[rt][dt][r] - mu) * rs * g_o[d] + b_o[d];
                }
            }
        }
    }
}

extern "C" void kernel_launch(void* const* d_in, const int* in_sizes, int n_in,
                              void* d_out, int out_size, void* d_ws, size_t ws_size,
                              hipStream_t stream)
{
    (void)in_sizes; (void)n_in; (void)out_size; (void)ws_size;
    const float* vals = (const float*)d_in[0];
    const float* keys = (const float*)d_in[1];
    const float* ques = (const float*)d_in[2];
    const float* Wv   = (const float*)d_in[5];
    const float* Wk   = (const float*)d_in[6];
    const float* Wq   = (const float*)d_in[7];
    const float* ln_k_g = (const float*)d_in[8];
    const float* ln_k_b = (const float*)d_in[9];
    const float* ln_q_g = (const float*)d_in[10];
    const float* ln_q_b = (const float*)d_in[11];
    const float* ln_o_g = (const float*)d_in[12];
    const float* ln_o_b = (const float*)d_in[13];
    float* outp = (float*)d_out;

    char* ws = (char*)d_ws;
    unsigned short* qbuf = (unsigned short*)(ws);
    unsigned short* kbuf = (unsigned short*)(ws + (size_t)16 * 1024 * 1024);
    unsigned short* vt   = (unsigned short*)(ws + (size_t)32 * 1024 * 1024);
    unsigned short* Wt   = (unsigned short*)(ws + (size_t)48 * 1024 * 1024);

    prep_w<<<dim3(1024, 3), 256, 0, stream>>>(Wv, Wk, Wq, Wt);

    gemm3<<<768, 512, 0, stream>>>(vals, keys, ques, Wt,
                                   ln_k_g, ln_k_b, ln_q_g, ln_q_b,
                                   vt, kbuf, qbuf);

    attn<<<256, 512, 0, stream>>>(qbuf, kbuf, vt, ques, ln_o_g, ln_o_b, outp);
}

// Round 13
// 211.642 us; speedup vs baseline: 1.7823x; 1.1247x over previous
//
#include <hip/hip_runtime.h>
#include <cstdint>

typedef short bf8 __attribute__((ext_vector_type(8)));
typedef float f4 __attribute__((ext_vector_type(4)));

#define SEQ 2048
#define DIM 512
#define NMAT (512*512)
#define SCQ 0.04419417382415922f
#define LOG2E 1.4426950408889634f

__device__ inline unsigned short f2bf(float f){
    unsigned int u = __builtin_bit_cast(unsigned int, f);
    u = (u + 0x7FFFu + ((u >> 16) & 1u)) >> 16;
    return (unsigned short)u;
}

__device__ __forceinline__ float exp2fast(float x){
    return __builtin_amdgcn_exp2f(x);   // v_exp_f32 (base-2 native)
}

__device__ __forceinline__ void glds16(const unsigned short* gsrc, const unsigned short* ldst){
    __builtin_amdgcn_global_load_lds(
        (const __attribute__((address_space(1))) unsigned int*)gsrc,
        (__attribute__((address_space(3))) unsigned int*)ldst, 16, 0, 0);
}

// DPP butterfly reduce steps (VALU, ~4 cyc) replacing ds_bpermute shfl (~120 cyc).
// 0xB1=quad_perm xor1, 0x4E=quad_perm xor2, 0x141=row_half_mirror, 0x140=row_mirror.
template<int CTRL>
__device__ __forceinline__ float dppadd(float x){
    const int t = __builtin_amdgcn_update_dpp(0, __builtin_bit_cast(int, x), CTRL, 0xF, 0xF, true);
    return x + __builtin_bit_cast(float, t);
}
template<int CTRL>
__device__ __forceinline__ float dppmax(float x){
    const int t = __builtin_amdgcn_update_dpp(0, __builtin_bit_cast(int, x), CTRL, 0xF, 0xF, true);
    return fmaxf(x, __builtin_bit_cast(float, t));
}

// ---------------- kernel 0: W (f32 [k][n]) -> Wt (bf16 [n][k]), coalesced ----------------
// 64x64 tile per block via LDS transpose: coalesced f32 reads, coalesced bf16 writes.
__global__ void prep_w(const float* __restrict__ Wv, const float* __restrict__ Wk,
                       const float* __restrict__ Wq, unsigned short* __restrict__ Wt)
{
    __shared__ float t_lds[64][65];
    const int m = blockIdx.y;
    const float* W = (m == 0) ? Wv : ((m == 1) ? Wk : Wq);
    const int bn = (blockIdx.x & 7) * 64;
    const int bk = (blockIdx.x >> 3) * 64;
    const int tr = threadIdx.x >> 6;
    const int tc = threadIdx.x & 63;
    #pragma unroll
    for (int i = 0; i < 16; ++i){
        const int k = tr + 4 * i;
        t_lds[k][tc] = W[(size_t)(bk + k) * 512 + bn + tc];
    }
    __syncthreads();
    #pragma unroll
    for (int i = 0; i < 16; ++i){
        const int n = tr + 4 * i;
        Wt[(size_t)m * NMAT + (size_t)(bn + n) * 512 + bk + tc] = f2bf(t_lds[tc][n]);
    }
}

// ---------------- kernel 1: fused 3x GEMM (+LN / +transpose epilogue) ----------------
__global__ __launch_bounds__(512, 1) void gemm3(
    const float* __restrict__ vals, const float* __restrict__ keys, const float* __restrict__ ques,
    const unsigned short* __restrict__ Wt,
    const float* __restrict__ kg, const float* __restrict__ kbe,
    const float* __restrict__ qg, const float* __restrict__ qbe,
    unsigned short* __restrict__ vt, unsigned short* __restrict__ kbuf, unsigned short* __restrict__ qbuf)
{
    __shared__ unsigned short a_lds[64 * DIM];   // 64 KB, XOR-swizzled rows
    float* red1    = (float*)a_lds;
    float* red2    = red1 + 512;
    float* stat_mu = red2 + 512;
    float* stat_rs = stat_mu + 64;

    const int tid = threadIdx.x;
    const int wv  = tid >> 6;
    const int l   = tid & 63;
    const int g   = l >> 4;
    const int lr  = l & 15;
    const int gid = blockIdx.x;
    const int m   = gid >> 8;            // 0=v, 1=k, 2=q
    const int r0  = (gid & 255) * 64;
    const float* X = (m == 0) ? vals : ((m == 1) ? keys : ques);
    const unsigned short* W = Wt + m * NMAT;

    {
        const int row = tid >> 3;
        const int cb  = (tid & 7) * 4;
        const float* xr = X + (size_t)(r0 + row) * DIM;
        #pragma unroll
        for (int i = 0; i < 16; ++i){
            const int col = cb + i * 32;
            const float4 v = *reinterpret_cast<const float4*>(xr + col);
            ushort4 h;
            h.x = f2bf(v.x); h.y = f2bf(v.y); h.z = f2bf(v.z); h.w = f2bf(v.w);
            const int byte = ((row * DIM + col) * 2) ^ ((row & 7) << 4);
            *reinterpret_cast<ushort4*>(reinterpret_cast<char*>(a_lds) + byte) = h;
        }
    }
    __syncthreads();

    f4 acc[4][4];
    #pragma unroll
    for (int i = 0; i < 4; ++i)
        #pragma unroll
        for (int j = 0; j < 4; ++j)
            acc[i][j] = (f4){0.f, 0.f, 0.f, 0.f};

    const int nb = wv * 64;
    #pragma unroll 4
    for (int ks = 0; ks < 16; ++ks){
        const int kof = ks * 32 + g * 8;
        bf8 af[4], bfr[4];
        #pragma unroll
        for (int rt = 0; rt < 4; ++rt){
            const int row = 16 * rt + lr;
            const int byte = ((row * DIM + kof) * 2) ^ ((row & 7) << 4);
            af[rt] = *reinterpret_cast<const bf8*>(reinterpret_cast<const char*>(a_lds) + byte);
        }
        #pragma unroll
        for (int ct = 0; ct < 4; ++ct)
            bfr[ct] = *reinterpret_cast<const bf8*>(W + (size_t)(nb + 16 * ct + lr) * DIM + kof);
        #pragma unroll
        for (int rt = 0; rt < 4; ++rt)
            #pragma unroll
            for (int ct = 0; ct < 4; ++ct)
                acc[rt][ct] = __builtin_amdgcn_mfma_f32_16x16x32_bf16(af[rt], bfr[ct], acc[rt][ct], 0, 0, 0);
    }

    if (m == 0){
        __syncthreads();
        #pragma unroll
        for (int rt = 0; rt < 4; ++rt)
            #pragma unroll
            for (int r = 0; r < 4; ++r){
                const int row = 16 * rt + g * 4 + r;
                #pragma unroll
                for (int ct = 0; ct < 4; ++ct){
                    const int d = nb + 16 * ct + lr;
                    const int byte = (d * 128 + row * 2) ^ ((d & 7) << 4);
                    *reinterpret_cast<unsigned short*>(reinterpret_cast<char*>(a_lds) + byte) = f2bf(acc[rt][ct][r]);
                }
            }
        __syncthreads();
        const int bb = r0 >> 11;
        const int s0 = r0 & 2047;
        #pragma unroll
        for (int pq = 0; pq < 4; ++pq){
            const int d  = pq * 128 + (tid >> 2);
            const int sc = (tid & 3) * 16;
            const int base = d * 128 + sc * 2;
            const int sw = (d & 7) << 4;
            const bf8 x0 = *reinterpret_cast<const bf8*>(reinterpret_cast<const char*>(a_lds) + (base ^ sw));
            const bf8 x1 = *reinterpret_cast<const bf8*>(reinterpret_cast<const char*>(a_lds) + ((base + 16) ^ sw));
            unsigned short* dst = vt + (size_t)(bb * 512 + d) * SEQ + s0 + sc;
            *reinterpret_cast<bf8*>(dst)     = x0;
            *reinterpret_cast<bf8*>(dst + 8) = x1;
        }
        return;
    }

    const float* gamma = (m == 1) ? kg  : qg;
    const float* beta  = (m == 1) ? kbe : qbe;
    // q gets SCQ * log2(e): softmax runs in exp2 domain
    const float scale  = (m == 1) ? 1.0f : SCQ * LOG2E;
    unsigned short* outp = (m == 1) ? kbuf : qbuf;

    __syncthreads();
    #pragma unroll
    for (int rt = 0; rt < 4; ++rt){
        #pragma unroll
        for (int r = 0; r < 4; ++r){
            float s1 = 0.f, s2 = 0.f;
            #pragma unroll
            for (int ct = 0; ct < 4; ++ct){ const float v = acc[rt][ct][r]; s1 += v; s2 += v * v; }
            #pragma unroll
            for (int mm = 1; mm < 16; mm <<= 1){ s1 += __shfl_xor(s1, mm, 64); s2 += __shfl_xor(s2, mm, 64); }
            if (lr == 0){
                const int row = 16 * rt + g * 4 + r;
                red1[row * 8 + wv] = s1;
                red2[row * 8 + wv] = s2;
            }
        }
    }
    __syncthreads();
    if (tid < 64){
        float S1 = 0.f, S2 = 0.f;
        #pragma unroll
        for (int w = 0; w < 8; ++w){ S1 += red1[tid * 8 + w]; S2 += red2[tid * 8 + w]; }
        const float mu = S1 * (1.0f / 512.0f);
        const float var = S2 * (1.0f / 512.0f) - mu * mu;
        stat_mu[tid] = mu;
        stat_rs[tid] = rsqrtf(var + 1e-5f);
    }
    __syncthreads();
    #pragma unroll
    for (int rt = 0; rt < 4; ++rt){
        #pragma unroll
        for (int r = 0; r < 4; ++r){
            const int row = 16 * rt + g * 4 + r;
            const float mu = stat_mu[row];
            const float rs = stat_rs[row];
            #pragma unroll
            for (int ct = 0; ct < 4; ++ct){
                const int d = nb + 16 * ct + lr;
                const float v = ((acc[rt][ct][r] - mu) * rs * gamma[d] + beta[d]) * scale;
                outp[(size_t)(r0 + row) * DIM + d] = f2bf(v);
            }
        }
    }
}

// ---------------- kernel 2: flash attention, KB=64, frozen-iteration rebalance ----------------
// grid 256 = 8 batch * 32 p. Rows 0-31 = qt=p (light), rows 32-63 = qt=63-p.
// Round-9 structure (ring-4, b1=lgkm, b2=vmcnt(8), DPP reduces, m/l in regs, exp2).
// NEW: on the critical low-p blocks most iterations are "frozen" (light rows done);
// previously QK fell to 4 waves and softmax to 4 waves -> 1 active wave/SIMD.
// Rebalance: (a) after j==jL, waves 0-3 RELOAD qf with the heavy rows' Q (same regs)
// and frozen QK splits by kv-half: waves 4-7 do h=0, waves 0-3 do h=1 (16 MFMA each,
// all 8 waves). (b) softmax rows bit-permuted so each wave owns 4 light + 4 heavy
// rows (8-lane groups preserved for DPP) -> all waves half-active when frozen.
__global__ __launch_bounds__(512, 2) void attn(
    const unsigned short* __restrict__ qb, const unsigned short* __restrict__ kb,
    const unsigned short* __restrict__ vt, const float* __restrict__ qin,
    const float* __restrict__ g_o, const float* __restrict__ b_o,
    float* __restrict__ outp)
{
    __shared__ unsigned short k_lds[4 * 32 * DIM];   // 128 KB ring-4, swizzled content
    __shared__ float s_lds[64][68];                  // 17.4 KB: 64x64 S + pad
    __shared__ unsigned short p_lds[64 * 64];        // 8 KB: 128B rows, XOR swz
    __shared__ float l_lds[64], fac_lds[64];
    // epilogue reduction arrays alias s_lds (dead after last softmax)
    float* red1    = &s_lds[0][0];
    float* red2    = red1 + 512;
    float* stat_mu = red2 + 512;
    float* stat_rs = stat_mu + 64;

    const int tid = threadIdx.x;
    const int wv  = tid >> 6;
    const int l   = tid & 63;
    const int g   = l >> 4;
    const int lr  = l & 15;
    const int b   = blockIdx.x & 7;
    const int p   = blockIdx.x >> 3;      // 0..31
    const int q0a = 32 * p;               // rows 0..31  (light)
    const int q0b = 32 * (63 - p);        // rows 32..63 (heavy)
    const int n2  = (65 - p) >> 1;        // kv pairs (17..32)
    const int jL  = p >> 1;               // last pair with light rows active (jL < n2-1 always)

    const int ct  = wv & 1;               // QK col tile (16 cols within 32-tile)
    const int rt_ = wv >> 1;              // QK row tile (16 rows), 0..3

    // softmax thread->row bit-permute: wave owns 4 light + 4 heavy rows.
    // sidx bits [b5b4b3|b2|b1b0] -> srow = b1b0 | (b5b4b3)<<2 | b2<<5 (bijective;
    // 8-lane row groups preserved so DPP 0xB1/0x4E/0x141 stay within a row).
    const int sidx = tid >> 3;
    const int scp  = tid & 7;
    const int srow_sm = (sidx & 3) | (((sidx >> 3)) << 2) | (((sidx >> 2) & 1) << 5);

    // Q fragments: rows 16*rt_+lr, full K=512 (qf[16] = 64 VGPR).
    // Waves 0-3 reload with heavy rows after j==jL (light rows retire).
    bf8 qf[16];
    {
        const int row = 16 * rt_ + lr;
        const int qglob = (row < 32) ? (q0a + row) : (q0b + row - 32);
        const unsigned short* qr = qb + (size_t)(b * SEQ + qglob) * DIM + g * 8;
        #pragma unroll
        for (int ks = 0; ks < 16; ++ks)
            qf[ks] = *reinterpret_cast<const bf8*>(qr + ks * 32);
    }

    // K staging: glds, linear dest + inverse-swizzled source (rows 4wv..4wv+3)
    auto kglds = [&](int t){
        const int bo = (t & 3) * (32 * DIM);
        #pragma unroll
        for (int i = 0; i < 4; ++i){
            const int row = 4 * wv + i;
            glds16(kb + (size_t)(b * SEQ + t * 32 + row) * DIM + ((l * 8) ^ ((row & 7) * 8)),
                   k_lds + bo + row * DIM);
        }
    };

    kglds(0);
    kglds(1);

    // running softmax stats in REGISTERS (srow_sm thread-stable; 8 copies/row)
    float m_reg = -__builtin_inff();
    float l_reg = 0.0f;

    f4 acc[4][4];
    #pragma unroll
    for (int rt = 0; rt < 4; ++rt)
        #pragma unroll
        for (int cv = 0; cv < 4; ++cv)
            acc[rt][cv] = (f4){0.f, 0.f, 0.f, 0.f};
    bf8 vst[8];   // [cv][ks]: V fragments for current 64-kv chunk

    // prologue drain: K(0), K(1), Q frags
    asm volatile("s_waitcnt vmcnt(0)" ::: "memory");
    __builtin_amdgcn_s_barrier();
    __builtin_amdgcn_sched_barrier(0);

    // PV helper: consumes p_lds/fac (pair jp) + vst (V of pair jp)
    auto do_pv = [&](int jp){
        const bool frozen = (jp > jL);
        __builtin_amdgcn_s_setprio(1);
        #pragma unroll
        for (int rt = 0; rt < 4; ++rt){
            if (rt < 2 && frozen) continue;    // light rows frozen
            float f[4];
            #pragma unroll
            for (int r = 0; r < 4; ++r) f[r] = fac_lds[16 * rt + 4 * g + r];
            #pragma unroll
            for (int cv = 0; cv < 4; ++cv)
                #pragma unroll
                for (int r = 0; r < 4; ++r)
                    acc[rt][cv][r] *= f[r];
            const int prow = 16 * rt + lr;
            const int sw = (prow & 7) << 4;
            const bf8 pa0 = *reinterpret_cast<const bf8*>(
                reinterpret_cast<const char*>(p_lds) + prow * 128 + ((g * 16) ^ sw));
            const bf8 pa1 = *reinterpret_cast<const bf8*>(
                reinterpret_cast<const char*>(p_lds) + prow * 128 + ((64 + g * 16) ^ sw));
            #pragma unroll
            for (int cv = 0; cv < 4; ++cv){
                acc[rt][cv] = __builtin_amdgcn_mfma_f32_16x16x32_bf16(pa0, vst[2 * cv],     acc[rt][cv], 0, 0, 0);
                acc[rt][cv] = __builtin_amdgcn_mfma_f32_16x16x32_bf16(pa1, vst[2 * cv + 1], acc[rt][cv], 0, 0, 0);
            }
        }
        __builtin_amdgcn_s_setprio(0);
    };

    // one QK half-tile: S(rt, ct, kv-half h) over full K=512, using current qf
    auto qk_half = [&](int rtu, int h, int j){
        const int krow  = 16 * ct + lr;
        const int rbase = krow * 1024;
        const int rx    = (krow & 7) << 4;
        const char* kbuf = reinterpret_cast<const char*>(k_lds) + ((2 * j + h) & 3) * 32768;
        f4 sa[4];
        sa[0] = (f4){0.f,0.f,0.f,0.f}; sa[1] = (f4){0.f,0.f,0.f,0.f};
        sa[2] = (f4){0.f,0.f,0.f,0.f}; sa[3] = (f4){0.f,0.f,0.f,0.f};
        #pragma unroll
        for (int ks = 0; ks < 16; ++ks){
            const bf8 bk = *reinterpret_cast<const bf8*>(
                kbuf + rbase + ((ks * 64 + g * 16) ^ rx));
            sa[ks & 3] = __builtin_amdgcn_mfma_f32_16x16x32_bf16(qf[ks], bk, sa[ks & 3], 0, 0, 0);
        }
        const f4 s = (sa[0] + sa[1]) + (sa[2] + sa[3]);
        const int srow = 16 * rtu + 4 * g;
        #pragma unroll
        for (int r = 0; r < 4; ++r)
            s_lds[srow + r][32 * h + 16 * ct + lr] = s[r];
    };

    for (int j = 0; j < n2; ++j){
        const int k0 = 64 * j;
        const int tp = 2 * j + 2;
        if (tp     < 2 * n2) kglds(tp);
        if (tp + 1 < 2 * n2) kglds(tp + 1);

        // ---- PV for previous pair (vst = V(j-1)) ----
        if (j > 0) do_pv(j - 1);

        // ---- V(j) loads: 64 kv cols (consumed next iter / final) ----
        #pragma unroll
        for (int cv = 0; cv < 4; ++cv)
            #pragma unroll
            for (int ks = 0; ks < 2; ++ks)
                vst[2 * cv + ks] = *reinterpret_cast<const bf8*>(
                    vt + (size_t)(b * DIM + 64 * wv + 16 * cv + lr) * SEQ + k0 + 32 * ks + g * 8);

        // ---- QK(j): full iters = own rt, both halves; frozen = heavy tiles
        //      split h-wise across ALL 8 waves (waves 0-3 use reloaded heavy qf) ----
        __builtin_amdgcn_s_setprio(1);
        if (j <= jL){
            qk_half(rt_, 0, j);
            qk_half(rt_, 1, j);
        } else if (wv >= 4){
            qk_half(rt_, 0, j);
        } else {
            qk_half(2 + (wv >> 1), 1, j);
        }
        __builtin_amdgcn_s_setprio(0);

        // b1: S visible; NO vmem drain (K/V loads stay in flight)
        asm volatile("s_waitcnt lgkmcnt(0)" ::: "memory");
        __builtin_amdgcn_s_barrier();
        __builtin_amdgcn_sched_barrier(0);

        // ---- softmax: bit-permuted rows (4 light + 4 heavy per wave), 8 cols/thread ----
        {
            const int row = srow_sm;
            const int cp  = scp;
            if (row >= 32 || j <= jL){
                const float4 x0 = *reinterpret_cast<const float4*>(&s_lds[row][8 * cp]);
                const float4 x1 = *reinterpret_cast<const float4*>(&s_lds[row][8 * cp + 4]);
                float av[8] = {x0.x, x0.y, x0.z, x0.w, x1.x, x1.y, x1.z, x1.w};
                const int qrow = (row < 32) ? (q0a + row) : (q0b + row - 32);
                const int kc = k0 + 8 * cp;
                #pragma unroll
                for (int jj = 0; jj < 8; ++jj)
                    if (kc + jj > qrow) av[jj] = -1e30f;
                float pm = fmaxf(fmaxf(fmaxf(av[0], av[1]), fmaxf(av[2], av[3])),
                                 fmaxf(fmaxf(av[4], av[5]), fmaxf(av[6], av[7])));
                pm = dppmax<0xB1>(pm); pm = dppmax<0x4E>(pm); pm = dppmax<0x141>(pm);
                const float mo = m_reg;
                const float mn = fmaxf(mo, pm);
                float e[8];
                #pragma unroll
                for (int jj = 0; jj < 8; ++jj) e[jj] = exp2fast(av[jj] - mn);
                float ts = ((e[0] + e[1]) + (e[2] + e[3])) + ((e[4] + e[5]) + (e[6] + e[7]));
                ts = dppadd<0xB1>(ts); ts = dppadd<0x4E>(ts); ts = dppadd<0x141>(ts);
                const float fc = exp2fast(mo - mn);
                m_reg = mn;
                l_reg = l_reg * fc + ts;
                if (cp == 0) fac_lds[row] = fc;
                uint4 pk;
                pk.x = (unsigned int)f2bf(e[0]) | ((unsigned int)f2bf(e[1]) << 16);
                pk.y = (unsigned int)f2bf(e[2]) | ((unsigned int)f2bf(e[3]) << 16);
                pk.z = (unsigned int)f2bf(e[4]) | ((unsigned int)f2bf(e[5]) << 16);
                pk.w = (unsigned int)f2bf(e[6]) | ((unsigned int)f2bf(e[7]) << 16);
                *reinterpret_cast<uint4*>(reinterpret_cast<char*>(p_lds) +
                    row * 128 + ((cp * 16) ^ ((row & 7) << 4))) = pk;
            }
        }
        // b2: P/fac visible AND prefetched K landed (8 glds drained; 8 V loads in flight)
        asm volatile("s_waitcnt vmcnt(8)" ::: "memory");
        asm volatile("s_waitcnt lgkmcnt(0)" ::: "memory");
        __builtin_amdgcn_s_barrier();
        __builtin_amdgcn_sched_barrier(0);

        // ---- heavy-Q reload for waves 0-3: light rows retired after jL ----
        if (wv < 4 && j == jL){
            const int qglob = q0b + 16 * (wv >> 1) + lr;   // heavy rows 32+16*(wv>>1)
            const unsigned short* qr = qb + (size_t)(b * SEQ + qglob) * DIM + g * 8;
            #pragma unroll
            for (int ks = 0; ks < 16; ++ks)
                qf[ks] = *reinterpret_cast<const bf8*>(qr + ks * 32);
        }
    }

    // publish register l to LDS for the epilogue's (different) thread mapping
    if (scp == 0) l_lds[srow_sm] = l_reg;

    // final PV (softmax/V of pair n2-1)
    asm volatile("s_waitcnt vmcnt(0)" ::: "memory");
    do_pv(n2 - 1);
    __syncthreads();   // l_lds visible to all

    // ---- finalize: /l, +residual, LN, store (64 rows) ----
    float li[4][4];
    #pragma unroll
    for (int rt = 0; rt < 4; ++rt)
        #pragma unroll
        for (int r = 0; r < 4; ++r)
            li[rt][r] = 1.0f / l_lds[16 * rt + 4 * g + r];
    #pragma unroll
    for (int rt = 0; rt < 4; ++rt){
        #pragma unroll
        for (int cv = 0; cv < 4; ++cv){
            #pragma unroll
            for (int r = 0; r < 4; ++r){
                const int row = 16 * rt + 4 * g + r;
                const int qglob = (row < 32) ? (q0a + row) : (q0b + row - 32);
                const int d = 64 * wv + 16 * cv + lr;
                acc[rt][cv][r] = acc[rt][cv][r] * li[rt][r]
                               + qin[(size_t)(b * SEQ + qglob) * DIM + d];
            }
        }
    }
    __syncthreads();   // s_lds reads fully done (aliased by red1/red2 below)
    #pragma unroll
    for (int rt = 0; rt < 4; ++rt){
        #pragma unroll
        for (int r = 0; r < 4; ++r){
            float s1 = 0.f, s2 = 0.f;
            #pragma unroll
            for (int cv = 0; cv < 4; ++cv){ const float v = acc[rt][cv][r]; s1 += v; s2 += v * v; }
            s1 = dppadd<0xB1>(s1); s1 = dppadd<0x4E>(s1); s1 = dppadd<0x141>(s1); s1 = dppadd<0x140>(s1);
            s2 = dppadd<0xB1>(s2); s2 = dppadd<0x4E>(s2); s2 = dppadd<0x141>(s2); s2 = dppadd<0x140>(s2);
            if (lr == 0){
                const int row = 16 * rt + 4 * g + r;
                red1[row * 8 + wv] = s1;
                red2[row * 8 + wv] = s2;
            }
        }
    }
    __syncthreads();
    if (tid < 64){
        float S1 = 0.f, S2 = 0.f;
        #pragma unroll
        for (int w = 0; w < 8; ++w){ S1 += red1[tid * 8 + w]; S2 += red2[tid * 8 + w]; }
        const float mu = S1 * (1.0f / 512.0f);
        const float var = S2 * (1.0f / 512.0f) - mu * mu;
        stat_mu[tid] = mu;
        stat_rs[tid] = rsqrtf(var + 1e-5f);
    }
    __syncthreads();
    #pragma unroll
    for (int rt = 0; rt < 4; ++rt){
        #pragma unroll
        for (int r = 0; r < 4; ++r){
            const int row = 16 * rt + 4 * g + r;
            const int qglob = (row < 32) ? (q0a + row) : (q0b + row - 32);
            const float mu = stat_mu[row];
            const float rs = stat_rs[row];
            #pragma unroll
            for (int cv = 0; cv < 4; ++cv){
                const int d = 64 * wv + 16 * cv + lr;
                outp[(size_t)(b * SEQ + qglob) * DIM + d] =
                    (acc[rt][cv][r] - mu) * rs * g_o[d] + b_o[d];
            }
        }
    }
}

extern "C" void kernel_launch(void* const* d_in, const int* in_sizes, int n_in,
                              void* d_out, int out_size, void* d_ws, size_t ws_size,
                              hipStream_t stream)
{
    (void)in_sizes; (void)n_in; (void)out_size; (void)ws_size;
    const float* vals = (const float*)d_in[0];
    const float* keys = (const float*)d_in[1];
    const float* ques = (const float*)d_in[2];
    const float* Wv   = (const float*)d_in[5];
    const float* Wk   = (const float*)d_in[6];
    const float* Wq   = (const float*)d_in[7];
    const float* ln_k_g = (const float*)d_in[8];
    const float* ln_k_b = (const float*)d_in[9];
    const float* ln_q_g = (const float*)d_in[10];
    const float* ln_q_b = (const float*)d_in[11];
    const float* ln_o_g = (const float*)d_in[12];
    const float* ln_o_b = (const float*)d_in[13];
    float* outp = (float*)d_out;

    char* ws = (char*)d_ws;
    unsigned short* qbuf = (unsigned short*)(ws);
    unsigned short* kbuf = (unsigned short*)(ws + (size_t)16 * 1024 * 1024);
    unsigned short* vt   = (unsigned short*)(ws + (size_t)32 * 1024 * 1024);
    unsigned short* Wt   = (unsigned short*)(ws + (size_t)48 * 1024 * 1024);

    prep_w<<<dim3(64, 3), 256, 0, stream>>>(Wv, Wk, Wq, Wt);

    gemm3<<<768, 512, 0, stream>>>(vals, keys, ques, Wt,
                                   ln_k_g, ln_k_b, ln_q_g, ln_q_b,
                                   vt, kbuf, qbuf);

    attn<<<256, 512, 0, stream>>>(qbuf, kbuf, vt, ques, ln_o_g, ln_o_b, outp);
}

// Round 14
// 185.474 us; speedup vs baseline: 2.0338x; 1.1411x over previous
//
#include <hip/hip_runtime.h>
#include <cstdint>

typedef short bf8 __attribute__((ext_vector_type(8)));
typedef float f4 __attribute__((ext_vector_type(4)));

#define SEQ 2048
#define DIM 512
#define NMAT (512*512)
#define SCQ 0.04419417382415922f
#define LOG2E 1.4426950408889634f

__device__ inline unsigned short f2bf(float f){
    unsigned int u = __builtin_bit_cast(unsigned int, f);
    u = (u + 0x7FFFu + ((u >> 16) & 1u)) >> 16;
    return (unsigned short)u;
}

__device__ __forceinline__ float exp2fast(float x){
    return __builtin_amdgcn_exp2f(x);   // v_exp_f32 (base-2 native)
}

__device__ __forceinline__ void glds16(const unsigned short* gsrc, const unsigned short* ldst){
    __builtin_amdgcn_global_load_lds(
        (const __attribute__((address_space(1))) unsigned int*)gsrc,
        (__attribute__((address_space(3))) unsigned int*)ldst, 16, 0, 0);
}

// DPP butterfly reduce steps (VALU, ~4 cyc) replacing ds_bpermute shfl (~120 cyc).
// 0xB1=quad_perm xor1, 0x4E=quad_perm xor2, 0x141=row_half_mirror, 0x140=row_mirror.
template<int CTRL>
__device__ __forceinline__ float dppadd(float x){
    const int t = __builtin_amdgcn_update_dpp(0, __builtin_bit_cast(int, x), CTRL, 0xF, 0xF, true);
    return x + __builtin_bit_cast(float, t);
}
template<int CTRL>
__device__ __forceinline__ float dppmax(float x){
    const int t = __builtin_amdgcn_update_dpp(0, __builtin_bit_cast(int, x), CTRL, 0xF, 0xF, true);
    return fmaxf(x, __builtin_bit_cast(float, t));
}

// ---------------- kernel 0: W (f32 [k][n]) -> Wt (bf16 [n][k]), coalesced ----------------
// 64x64 tile per block via LDS transpose: coalesced f32 reads, coalesced bf16 writes.
__global__ void prep_w(const float* __restrict__ Wv, const float* __restrict__ Wk,
                       const float* __restrict__ Wq, unsigned short* __restrict__ Wt)
{
    __shared__ float t_lds[64][65];
    const int m = blockIdx.y;
    const float* W = (m == 0) ? Wv : ((m == 1) ? Wk : Wq);
    const int bn = (blockIdx.x & 7) * 64;
    const int bk = (blockIdx.x >> 3) * 64;
    const int tr = threadIdx.x >> 6;
    const int tc = threadIdx.x & 63;
    #pragma unroll
    for (int i = 0; i < 16; ++i){
        const int k = tr + 4 * i;
        t_lds[k][tc] = W[(size_t)(bk + k) * 512 + bn + tc];
    }
    __syncthreads();
    #pragma unroll
    for (int i = 0; i < 16; ++i){
        const int n = tr + 4 * i;
        Wt[(size_t)m * NMAT + (size_t)(bn + n) * 512 + bk + tc] = f2bf(t_lds[tc][n]);
    }
}

// ---------------- kernel 1: fused 3x GEMM (+LN / +transpose epilogue) ----------------
__global__ __launch_bounds__(512, 1) void gemm3(
    const float* __restrict__ vals, const float* __restrict__ keys, const float* __restrict__ ques,
    const unsigned short* __restrict__ Wt,
    const float* __restrict__ kg, const float* __restrict__ kbe,
    const float* __restrict__ qg, const float* __restrict__ qbe,
    unsigned short* __restrict__ vt, unsigned short* __restrict__ kbuf, unsigned short* __restrict__ qbuf)
{
    __shared__ unsigned short a_lds[64 * DIM];   // 64 KB, XOR-swizzled rows
    float* red1    = (float*)a_lds;
    float* red2    = red1 + 512;
    float* stat_mu = red2 + 512;
    float* stat_rs = stat_mu + 64;

    const int tid = threadIdx.x;
    const int wv  = tid >> 6;
    const int l   = tid & 63;
    const int g   = l >> 4;
    const int lr  = l & 15;
    const int gid = blockIdx.x;
    const int m   = gid >> 8;            // 0=v, 1=k, 2=q
    const int r0  = (gid & 255) * 64;
    const float* X = (m == 0) ? vals : ((m == 1) ? keys : ques);
    const unsigned short* W = Wt + m * NMAT;

    {
        const int row = tid >> 3;
        const int cb  = (tid & 7) * 4;
        const float* xr = X + (size_t)(r0 + row) * DIM;
        #pragma unroll
        for (int i = 0; i < 16; ++i){
            const int col = cb + i * 32;
            const float4 v = *reinterpret_cast<const float4*>(xr + col);
            ushort4 h;
            h.x = f2bf(v.x); h.y = f2bf(v.y); h.z = f2bf(v.z); h.w = f2bf(v.w);
            const int byte = ((row * DIM + col) * 2) ^ ((row & 7) << 4);
            *reinterpret_cast<ushort4*>(reinterpret_cast<char*>(a_lds) + byte) = h;
        }
    }
    __syncthreads();

    f4 acc[4][4];
    #pragma unroll
    for (int i = 0; i < 4; ++i)
        #pragma unroll
        for (int j = 0; j < 4; ++j)
            acc[i][j] = (f4){0.f, 0.f, 0.f, 0.f};

    const int nb = wv * 64;
    #pragma unroll 4
    for (int ks = 0; ks < 16; ++ks){
        const int kof = ks * 32 + g * 8;
        bf8 af[4], bfr[4];
        #pragma unroll
        for (int rt = 0; rt < 4; ++rt){
            const int row = 16 * rt + lr;
            const int byte = ((row * DIM + kof) * 2) ^ ((row & 7) << 4);
            af[rt] = *reinterpret_cast<const bf8*>(reinterpret_cast<const char*>(a_lds) + byte);
        }
        #pragma unroll
        for (int ct = 0; ct < 4; ++ct)
            bfr[ct] = *reinterpret_cast<const bf8*>(W + (size_t)(nb + 16 * ct + lr) * DIM + kof);
        #pragma unroll
        for (int rt = 0; rt < 4; ++rt)
            #pragma unroll
            for (int ct = 0; ct < 4; ++ct)
                acc[rt][ct] = __builtin_amdgcn_mfma_f32_16x16x32_bf16(af[rt], bfr[ct], acc[rt][ct], 0, 0, 0);
    }

    if (m == 0){
        __syncthreads();
        #pragma unroll
        for (int rt = 0; rt < 4; ++rt)
            #pragma unroll
            for (int r = 0; r < 4; ++r){
                const int row = 16 * rt + g * 4 + r;
                #pragma unroll
                for (int ct = 0; ct < 4; ++ct){
                    const int d = nb + 16 * ct + lr;
                    const int byte = (d * 128 + row * 2) ^ ((d & 7) << 4);
                    *reinterpret_cast<unsigned short*>(reinterpret_cast<char*>(a_lds) + byte) = f2bf(acc[rt][ct][r]);
                }
            }
        __syncthreads();
        const int bb = r0 >> 11;
        const int s0 = r0 & 2047;
        #pragma unroll
        for (int pq = 0; pq < 4; ++pq){
            const int d  = pq * 128 + (tid >> 2);
            const int sc = (tid & 3) * 16;
            const int base = d * 128 + sc * 2;
            const int sw = (d & 7) << 4;
            const bf8 x0 = *reinterpret_cast<const bf8*>(reinterpret_cast<const char*>(a_lds) + (base ^ sw));
            const bf8 x1 = *reinterpret_cast<const bf8*>(reinterpret_cast<const char*>(a_lds) + ((base + 16) ^ sw));
            unsigned short* dst = vt + (size_t)(bb * 512 + d) * SEQ + s0 + sc;
            *reinterpret_cast<bf8*>(dst)     = x0;
            *reinterpret_cast<bf8*>(dst + 8) = x1;
        }
        return;
    }

    const float* gamma = (m == 1) ? kg  : qg;
    const float* beta  = (m == 1) ? kbe : qbe;
    // q gets SCQ * log2(e): softmax runs in exp2 domain (v_exp_f32 is base-2)
    const float scale  = (m == 1) ? 1.0f : SCQ * LOG2E;
    unsigned short* outp = (m == 1) ? kbuf : qbuf;

    __syncthreads();
    #pragma unroll
    for (int rt = 0; rt < 4; ++rt){
        #pragma unroll
        for (int r = 0; r < 4; ++r){
            float s1 = 0.f, s2 = 0.f;
            #pragma unroll
            for (int ct = 0; ct < 4; ++ct){ const float v = acc[rt][ct][r]; s1 += v; s2 += v * v; }
            // 16-lane reduce via DPP (was 4x2 ds_bpermute shfl chains)
            s1 = dppadd<0xB1>(s1); s1 = dppadd<0x4E>(s1); s1 = dppadd<0x141>(s1); s1 = dppadd<0x140>(s1);
            s2 = dppadd<0xB1>(s2); s2 = dppadd<0x4E>(s2); s2 = dppadd<0x141>(s2); s2 = dppadd<0x140>(s2);
            if (lr == 0){
                const int row = 16 * rt + g * 4 + r;
                red1[row * 8 + wv] = s1;
                red2[row * 8 + wv] = s2;
            }
        }
    }
    __syncthreads();
    if (tid < 64){
        float S1 = 0.f, S2 = 0.f;
        #pragma unroll
        for (int w = 0; w < 8; ++w){ S1 += red1[tid * 8 + w]; S2 += red2[tid * 8 + w]; }
        const float mu = S1 * (1.0f / 512.0f);
        const float var = S2 * (1.0f / 512.0f) - mu * mu;
        stat_mu[tid] = mu;
        stat_rs[tid] = rsqrtf(var + 1e-5f);
    }
    __syncthreads();
    #pragma unroll
    for (int rt = 0; rt < 4; ++rt){
        #pragma unroll
        for (int r = 0; r < 4; ++r){
            const int row = 16 * rt + g * 4 + r;
            const float mu = stat_mu[row];
            const float rs = stat_rs[row];
            #pragma unroll
            for (int ct = 0; ct < 4; ++ct){
                const int d = nb + 16 * ct + lr;
                const float v = ((acc[rt][ct][r] - mu) * rs * gamma[d] + beta[d]) * scale;
                outp[(size_t)(r0 + row) * DIM + d] = f2bf(v);
            }
        }
    }
}

// ---------------- kernel 2: flash attention, KB=64 (round-9 structure, reverted) ----------------
// grid 256 = 8 batch * 32 p. Rows 0-31 = qt=p (light), rows 32-63 = qt=63-p.
// Iteration j: phase1 = {glds K(2j+2,2j+3), PV(j-1), V(j) loads, QK(j)};
// b1 = lgkm only; phase2 = softmax(j) (exp2 domain, DPP reduces, m/l in regs);
// b2 = vmcnt(8) (drains 8 K glds, 8 V loads stay in flight). K ring-4 (128 KB).
__global__ __launch_bounds__(512, 2) void attn(
    const unsigned short* __restrict__ qb, const unsigned short* __restrict__ kb,
    const unsigned short* __restrict__ vt, const float* __restrict__ qin,
    const float* __restrict__ g_o, const float* __restrict__ b_o,
    float* __restrict__ outp)
{
    __shared__ unsigned short k_lds[4 * 32 * DIM];   // 128 KB ring-4, swizzled content
    __shared__ float s_lds[64][68];                  // 17.4 KB: 64x64 S + pad
    __shared__ unsigned short p_lds[64 * 64];        // 8 KB: 128B rows, XOR swz
    __shared__ float l_lds[64], fac_lds[64];
    // epilogue reduction arrays alias s_lds (dead after last softmax)
    float* red1    = &s_lds[0][0];
    float* red2    = red1 + 512;
    float* stat_mu = red2 + 512;
    float* stat_rs = stat_mu + 64;

    const int tid = threadIdx.x;
    const int wv  = tid >> 6;
    const int l   = tid & 63;
    const int g   = l >> 4;
    const int lr  = l & 15;
    const int b   = blockIdx.x & 7;
    const int p   = blockIdx.x >> 3;      // 0..31
    const int q0a = 32 * p;               // rows 0..31  (light)
    const int q0b = 32 * (63 - p);        // rows 32..63 (heavy)
    const int n2  = (65 - p) >> 1;        // kv pairs (17..32)
    const int jL  = p >> 1;               // last pair with light rows active

    const int ct  = wv & 1;               // QK col tile (16 cols within 32-tile)
    const int rt_ = wv >> 1;              // QK row tile (16 rows), 0..3

    // Q fragments: rows 16*rt_+lr, full K=512 (qf[16] = 64 VGPR)
    bf8 qf[16];
    {
        const int row = 16 * rt_ + lr;
        const int qglob = (row < 32) ? (q0a + row) : (q0b + row - 32);
        const unsigned short* qr = qb + (size_t)(b * SEQ + qglob) * DIM + g * 8;
        #pragma unroll
        for (int ks = 0; ks < 16; ++ks)
            qf[ks] = *reinterpret_cast<const bf8*>(qr + ks * 32);
    }

    // K staging: glds, linear dest + inverse-swizzled source (rows 4wv..4wv+3)
    auto kglds = [&](int t){
        const int bo = (t & 3) * (32 * DIM);
        #pragma unroll
        for (int i = 0; i < 4; ++i){
            const int row = 4 * wv + i;
            glds16(kb + (size_t)(b * SEQ + t * 32 + row) * DIM + ((l * 8) ^ ((row & 7) * 8)),
                   k_lds + bo + row * DIM);
        }
    };

    kglds(0);
    kglds(1);

    // running softmax stats in REGISTERS (row = tid>>3 is thread-stable;
    // all 8 threads of a row keep identical copies)
    float m_reg = -__builtin_inff();
    float l_reg = 0.0f;

    f4 acc[4][4];
    #pragma unroll
    for (int rt = 0; rt < 4; ++rt)
        #pragma unroll
        for (int cv = 0; cv < 4; ++cv)
            acc[rt][cv] = (f4){0.f, 0.f, 0.f, 0.f};
    bf8 vst[8];   // [cv][ks]: V fragments for current 64-kv chunk

    // prologue drain: K(0), K(1), Q frags
    asm volatile("s_waitcnt vmcnt(0)" ::: "memory");
    __builtin_amdgcn_s_barrier();
    __builtin_amdgcn_sched_barrier(0);

    // PV helper: consumes p_lds/fac (pair jp) + vst (V of pair jp)
    auto do_pv = [&](int jp){
        const bool frozen = (jp > jL);
        __builtin_amdgcn_s_setprio(1);
        #pragma unroll
        for (int rt = 0; rt < 4; ++rt){
            if (rt < 2 && frozen) continue;    // light rows frozen
            float f[4];
            #pragma unroll
            for (int r = 0; r < 4; ++r) f[r] = fac_lds[16 * rt + 4 * g + r];
            #pragma unroll
            for (int cv = 0; cv < 4; ++cv)
                #pragma unroll
                for (int r = 0; r < 4; ++r)
                    acc[rt][cv][r] *= f[r];
            const int prow = 16 * rt + lr;
            const int sw = (prow & 7) << 4;
            const bf8 pa0 = *reinterpret_cast<const bf8*>(
                reinterpret_cast<const char*>(p_lds) + prow * 128 + ((g * 16) ^ sw));
            const bf8 pa1 = *reinterpret_cast<const bf8*>(
                reinterpret_cast<const char*>(p_lds) + prow * 128 + ((64 + g * 16) ^ sw));
            #pragma unroll
            for (int cv = 0; cv < 4; ++cv){
                acc[rt][cv] = __builtin_amdgcn_mfma_f32_16x16x32_bf16(pa0, vst[2 * cv],     acc[rt][cv], 0, 0, 0);
                acc[rt][cv] = __builtin_amdgcn_mfma_f32_16x16x32_bf16(pa1, vst[2 * cv + 1], acc[rt][cv], 0, 0, 0);
            }
        }
        __builtin_amdgcn_s_setprio(0);
    };

    for (int j = 0; j < n2; ++j){
        const int k0 = 64 * j;
        const int tp = 2 * j + 2;
        if (tp     < 2 * n2) kglds(tp);
        if (tp + 1 < 2 * n2) kglds(tp + 1);

        // ---- PV for previous pair (vst = V(j-1)) ----
        if (j > 0) do_pv(j - 1);

        // ---- V(j) loads: 64 kv cols (consumed next iter / final) ----
        #pragma unroll
        for (int cv = 0; cv < 4; ++cv)
            #pragma unroll
            for (int ks = 0; ks < 2; ++ks)
                vst[2 * cv + ks] = *reinterpret_cast<const bf8*>(
                    vt + (size_t)(b * DIM + 64 * wv + 16 * cv + lr) * SEQ + k0 + 32 * ks + g * 8);

        // ---- QK(j): wave (rt_, ct), two 32-col halves, full K=512 each ----
        if (rt_ >= 2 || j <= jL){
            const int krow  = 16 * ct + lr;
            const int rbase = krow * 1024;
            const int rx    = (krow & 7) << 4;
            __builtin_amdgcn_s_setprio(1);
            #pragma unroll
            for (int h = 0; h < 2; ++h){
                const char* kbuf = reinterpret_cast<const char*>(k_lds) + ((2 * j + h) & 3) * 32768;
                f4 sa[4];
                sa[0] = (f4){0.f,0.f,0.f,0.f}; sa[1] = (f4){0.f,0.f,0.f,0.f};
                sa[2] = (f4){0.f,0.f,0.f,0.f}; sa[3] = (f4){0.f,0.f,0.f,0.f};
                #pragma unroll
                for (int ks = 0; ks < 16; ++ks){
                    const bf8 bk = *reinterpret_cast<const bf8*>(
                        kbuf + rbase + ((ks * 64 + g * 16) ^ rx));
                    sa[ks & 3] = __builtin_amdgcn_mfma_f32_16x16x32_bf16(qf[ks], bk, sa[ks & 3], 0, 0, 0);
                }
                const f4 s = (sa[0] + sa[1]) + (sa[2] + sa[3]);
                const int srow = 16 * rt_ + 4 * g;
                #pragma unroll
                for (int r = 0; r < 4; ++r)
                    s_lds[srow + r][32 * h + 16 * ct + lr] = s[r];
            }
            __builtin_amdgcn_s_setprio(0);
        }
        // b1: S visible; NO vmem drain (K/V loads stay in flight)
        asm volatile("s_waitcnt lgkmcnt(0)" ::: "memory");
        __builtin_amdgcn_s_barrier();
        __builtin_amdgcn_sched_barrier(0);

        // ---- softmax: row = tid>>3, 8 cols/thread over 64 kv cols ----
        // exp2 domain (log2e folded into q); DPP reduces; m/l in registers.
        {
            const int row = tid >> 3;
            const int cp  = tid & 7;
            if (row >= 32 || j <= jL){
                const float4 x0 = *reinterpret_cast<const float4*>(&s_lds[row][8 * cp]);
                const float4 x1 = *reinterpret_cast<const float4*>(&s_lds[row][8 * cp + 4]);
                float av[8] = {x0.x, x0.y, x0.z, x0.w, x1.x, x1.y, x1.z, x1.w};
                const int qrow = (row < 32) ? (q0a + row) : (q0b + row - 32);
                const int kc = k0 + 8 * cp;
                #pragma unroll
                for (int jj = 0; jj < 8; ++jj)
                    if (kc + jj > qrow) av[jj] = -1e30f;
                float pm = fmaxf(fmaxf(fmaxf(av[0], av[1]), fmaxf(av[2], av[3])),
                                 fmaxf(fmaxf(av[4], av[5]), fmaxf(av[6], av[7])));
                pm = dppmax<0xB1>(pm); pm = dppmax<0x4E>(pm); pm = dppmax<0x141>(pm);
                const float mo = m_reg;
                const float mn = fmaxf(mo, pm);
                float e[8];
                #pragma unroll
                for (int jj = 0; jj < 8; ++jj) e[jj] = exp2fast(av[jj] - mn);
                float ts = ((e[0] + e[1]) + (e[2] + e[3])) + ((e[4] + e[5]) + (e[6] + e[7]));
                ts = dppadd<0xB1>(ts); ts = dppadd<0x4E>(ts); ts = dppadd<0x141>(ts);
                const float fc = exp2fast(mo - mn);
                m_reg = mn;
                l_reg = l_reg * fc + ts;
                if (cp == 0) fac_lds[row] = fc;
                uint4 pk;
                pk.x = (unsigned int)f2bf(e[0]) | ((unsigned int)f2bf(e[1]) << 16);
                pk.y = (unsigned int)f2bf(e[2]) | ((unsigned int)f2bf(e[3]) << 16);
                pk.z = (unsigned int)f2bf(e[4]) | ((unsigned int)f2bf(e[5]) << 16);
                pk.w = (unsigned int)f2bf(e[6]) | ((unsigned int)f2bf(e[7]) << 16);
                *reinterpret_cast<uint4*>(reinterpret_cast<char*>(p_lds) +
                    row * 128 + ((cp * 16) ^ ((row & 7) << 4))) = pk;
            }
        }
        // b2: P/fac visible AND prefetched K landed (8 glds drained; 8 V loads in flight)
        asm volatile("s_waitcnt vmcnt(8)" ::: "memory");
        asm volatile("s_waitcnt lgkmcnt(0)" ::: "memory");
        __builtin_amdgcn_s_barrier();
        __builtin_amdgcn_sched_barrier(0);
    }

    // publish register l to LDS for the epilogue's (different) thread mapping
    if ((tid & 7) == 0) l_lds[tid >> 3] = l_reg;

    // final PV (softmax/V of pair n2-1)
    asm volatile("s_waitcnt vmcnt(0)" ::: "memory");
    do_pv(n2 - 1);
    __syncthreads();   // l_lds visible to all

    // ---- finalize: /l, +residual, LN, store (64 rows) ----
    float li[4][4];
    #pragma unroll
    for (int rt = 0; rt < 4; ++rt)
        #pragma unroll
        for (int r = 0; r < 4; ++r)
            li[rt][r] = 1.0f / l_lds[16 * rt + 4 * g + r];
    #pragma unroll
    for (int rt = 0; rt < 4; ++rt){
        #pragma unroll
        for (int cv = 0; cv < 4; ++cv){
            #pragma unroll
            for (int r = 0; r < 4; ++r){
                const int row = 16 * rt + 4 * g + r;
                const int qglob = (row < 32) ? (q0a + row) : (q0b + row - 32);
                const int d = 64 * wv + 16 * cv + lr;
                acc[rt][cv][r] = acc[rt][cv][r] * li[rt][r]
                               + qin[(size_t)(b * SEQ + qglob) * DIM + d];
            }
        }
    }
    __syncthreads();   // s_lds reads fully done (aliased by red1/red2 below)
    #pragma unroll
    for (int rt = 0; rt < 4; ++rt){
        #pragma unroll
        for (int r = 0; r < 4; ++r){
            float s1 = 0.f, s2 = 0.f;
            #pragma unroll
            for (int cv = 0; cv < 4; ++cv){ const float v = acc[rt][cv][r]; s1 += v; s2 += v * v; }
            s1 = dppadd<0xB1>(s1); s1 = dppadd<0x4E>(s1); s1 = dppadd<0x141>(s1); s1 = dppadd<0x140>(s1);
            s2 = dppadd<0xB1>(s2); s2 = dppadd<0x4E>(s2); s2 = dppadd<0x141>(s2); s2 = dppadd<0x140>(s2);
            if (lr == 0){
                const int row = 16 * rt + 4 * g + r;
                red1[row * 8 + wv] = s1;
                red2[row * 8 + wv] = s2;
            }
        }
    }
    __syncthreads();
    if (tid < 64){
        float S1 = 0.f, S2 = 0.f;
        #pragma unroll
        for (int w = 0; w < 8; ++w){ S1 += red1[tid * 8 + w]; S2 += red2[tid * 8 + w]; }
        const float mu = S1 * (1.0f / 512.0f);
        const float var = S2 * (1.0f / 512.0f) - mu * mu;
        stat_mu[tid] = mu;
        stat_rs[tid] = rsqrtf(var + 1e-5f);
    }
    __syncthreads();
    #pragma unroll
    for (int rt = 0; rt < 4; ++rt){
        #pragma unroll
        for (int r = 0; r < 4; ++r){
            const int row = 16 * rt + 4 * g + r;
            const int qglob = (row < 32) ? (q0a + row) : (q0b + row - 32);
            const float mu = stat_mu[row];
            const float rs = stat_rs[row];
            #pragma unroll
            for (int cv = 0; cv < 4; ++cv){
                const int d = 64 * wv + 16 * cv + lr;
                outp[(size_t)(b * SEQ + qglob) * DIM + d] =
                    (acc[rt][cv][r] - mu) * rs * g_o[d] + b_o[d];
            }
        }
    }
}

extern "C" void kernel_launch(void* const* d_in, const int* in_sizes, int n_in,
                              void* d_out, int out_size, void* d_ws, size_t ws_size,
                              hipStream_t stream)
{
    (void)in_sizes; (void)n_in; (void)out_size; (void)ws_size;
    const float* vals = (const float*)d_in[0];
    const float* keys = (const float*)d_in[1];
    const float* ques = (const float*)d_in[2];
    const float* Wv   = (const float*)d_in[5];
    const float* Wk   = (const float*)d_in[6];
    const float* Wq   = (const float*)d_in[7];
    const float* ln_k_g = (const float*)d_in[8];
    const float* ln_k_b = (const float*)d_in[9];
    const float* ln_q_g = (const float*)d_in[10];
    const float* ln_q_b = (const float*)d_in[11];
    const float* ln_o_g = (const float*)d_in[12];
    const float* ln_o_b = (const float*)d_in[13];
    float* outp = (float*)d_out;

    char* ws = (char*)d_ws;
    unsigned short* qbuf = (unsigned short*)(ws);
    unsigned short* kbuf = (unsigned short*)(ws + (size_t)16 * 1024 * 1024);
    unsigned short* vt   = (unsigned short*)(ws + (size_t)32 * 1024 * 1024);
    unsigned short* Wt   = (unsigned short*)(ws + (size_t)48 * 1024 * 1024);

    prep_w<<<dim3(64, 3), 256, 0, stream>>>(Wv, Wk, Wq, Wt);

    gemm3<<<768, 512, 0, stream>>>(vals, keys, ques, Wt,
                                   ln_k_g, ln_k_b, ln_q_g, ln_q_b,
                                   vt, kbuf, qbuf);

    attn<<<256, 512, 0, stream>>>(qbuf, kbuf, vt, ques, ln_o_g, ln_o_b, outp);
}

// Round 15
// 185.165 us; speedup vs baseline: 2.0372x; 1.0017x over previous
//
#include <hip/hip_runtime.h>
#include <cstdint>

typedef short bf8 __attribute__((ext_vector_type(8)));
typedef float f4 __attribute__((ext_vector_type(4)));

#define SEQ 2048
#define DIM 512
#define NMAT (512*512)
#define SCQ 0.04419417382415922f
#define LOG2E 1.4426950408889634f

__device__ inline unsigned short f2bf(float f){
    unsigned int u = __builtin_bit_cast(unsigned int, f);
    u = (u + 0x7FFFu + ((u >> 16) & 1u)) >> 16;
    return (unsigned short)u;
}

__device__ __forceinline__ float exp2fast(float x){
    return __builtin_amdgcn_exp2f(x);   // v_exp_f32 (base-2 native)
}

__device__ __forceinline__ void glds16(const unsigned short* gsrc, const unsigned short* ldst){
    __builtin_amdgcn_global_load_lds(
        (const __attribute__((address_space(1))) unsigned int*)gsrc,
        (__attribute__((address_space(3))) unsigned int*)ldst, 16, 0, 0);
}

// DPP butterfly reduce steps (VALU, ~4 cyc) replacing ds_bpermute shfl (~120 cyc).
// 0xB1=quad_perm xor1, 0x4E=quad_perm xor2, 0x141=row_half_mirror, 0x140=row_mirror.
template<int CTRL>
__device__ __forceinline__ float dppadd(float x){
    const int t = __builtin_amdgcn_update_dpp(0, __builtin_bit_cast(int, x), CTRL, 0xF, 0xF, true);
    return x + __builtin_bit_cast(float, t);
}
template<int CTRL>
__device__ __forceinline__ float dppmax(float x){
    const int t = __builtin_amdgcn_update_dpp(0, __builtin_bit_cast(int, x), CTRL, 0xF, 0xF, true);
    return fmaxf(x, __builtin_bit_cast(float, t));
}

// ---------------- kernel 0: W (f32 [k][n]) -> Wt (bf16 [n][k]), coalesced ----------------
// 64x64 tile per block via LDS transpose: coalesced f32 reads, coalesced bf16 writes.
__global__ void prep_w(const float* __restrict__ Wv, const float* __restrict__ Wk,
                       const float* __restrict__ Wq, unsigned short* __restrict__ Wt)
{
    __shared__ float t_lds[64][65];
    const int m = blockIdx.y;
    const float* W = (m == 0) ? Wv : ((m == 1) ? Wk : Wq);
    const int bn = (blockIdx.x & 7) * 64;
    const int bk = (blockIdx.x >> 3) * 64;
    const int tr = threadIdx.x >> 6;
    const int tc = threadIdx.x & 63;
    #pragma unroll
    for (int i = 0; i < 16; ++i){
        const int k = tr + 4 * i;
        t_lds[k][tc] = W[(size_t)(bk + k) * 512 + bn + tc];
    }
    __syncthreads();
    #pragma unroll
    for (int i = 0; i < 16; ++i){
        const int n = tr + 4 * i;
        Wt[(size_t)m * NMAT + (size_t)(bn + n) * 512 + bk + tc] = f2bf(t_lds[tc][n]);
    }
}

// ---------------- kernel 1: fused 3x GEMM (+LN / +transpose epilogue) ----------------
// __launch_bounds__(512, 4): 4 waves/EU -> 2 blocks/CU co-resident (LDS 2x64KB=128KB,
// VGPR capped at 128). Overlaps one block's staging/epilogue with another's K-loop
// and doubles the waves hiding the L2 latency of the in-loop W-fragment loads.
__global__ __launch_bounds__(512, 4) void gemm3(
    const float* __restrict__ vals, const float* __restrict__ keys, const float* __restrict__ ques,
    const unsigned short* __restrict__ Wt,
    const float* __restrict__ kg, const float* __restrict__ kbe,
    const float* __restrict__ qg, const float* __restrict__ qbe,
    unsigned short* __restrict__ vt, unsigned short* __restrict__ kbuf, unsigned short* __restrict__ qbuf)
{
    __shared__ unsigned short a_lds[64 * DIM];   // 64 KB, XOR-swizzled rows
    float* red1    = (float*)a_lds;
    float* red2    = red1 + 512;
    float* stat_mu = red2 + 512;
    float* stat_rs = stat_mu + 64;

    const int tid = threadIdx.x;
    const int wv  = tid >> 6;
    const int l   = tid & 63;
    const int g   = l >> 4;
    const int lr  = l & 15;
    const int gid = blockIdx.x;
    const int m   = gid >> 8;            // 0=v, 1=k, 2=q
    const int r0  = (gid & 255) * 64;
    const float* X = (m == 0) ? vals : ((m == 1) ? keys : ques);
    const unsigned short* W = Wt + m * NMAT;

    {
        const int row = tid >> 3;
        const int cb  = (tid & 7) * 4;
        const float* xr = X + (size_t)(r0 + row) * DIM;
        #pragma unroll
        for (int i = 0; i < 16; ++i){
            const int col = cb + i * 32;
            const float4 v = *reinterpret_cast<const float4*>(xr + col);
            ushort4 h;
            h.x = f2bf(v.x); h.y = f2bf(v.y); h.z = f2bf(v.z); h.w = f2bf(v.w);
            const int byte = ((row * DIM + col) * 2) ^ ((row & 7) << 4);
            *reinterpret_cast<ushort4*>(reinterpret_cast<char*>(a_lds) + byte) = h;
        }
    }
    __syncthreads();

    f4 acc[4][4];
    #pragma unroll
    for (int i = 0; i < 4; ++i)
        #pragma unroll
        for (int j = 0; j < 4; ++j)
            acc[i][j] = (f4){0.f, 0.f, 0.f, 0.f};

    const int nb = wv * 64;
    #pragma unroll 4
    for (int ks = 0; ks < 16; ++ks){
        const int kof = ks * 32 + g * 8;
        bf8 af[4], bfr[4];
        #pragma unroll
        for (int rt = 0; rt < 4; ++rt){
            const int row = 16 * rt + lr;
            const int byte = ((row * DIM + kof) * 2) ^ ((row & 7) << 4);
            af[rt] = *reinterpret_cast<const bf8*>(reinterpret_cast<const char*>(a_lds) + byte);
        }
        #pragma unroll
        for (int ct = 0; ct < 4; ++ct)
            bfr[ct] = *reinterpret_cast<const bf8*>(W + (size_t)(nb + 16 * ct + lr) * DIM + kof);
        #pragma unroll
        for (int rt = 0; rt < 4; ++rt)
            #pragma unroll
            for (int ct = 0; ct < 4; ++ct)
                acc[rt][ct] = __builtin_amdgcn_mfma_f32_16x16x32_bf16(af[rt], bfr[ct], acc[rt][ct], 0, 0, 0);
    }

    if (m == 0){
        __syncthreads();
        #pragma unroll
        for (int rt = 0; rt < 4; ++rt)
            #pragma unroll
            for (int r = 0; r < 4; ++r){
                const int row = 16 * rt + g * 4 + r;
                #pragma unroll
                for (int ct = 0; ct < 4; ++ct){
                    const int d = nb + 16 * ct + lr;
                    const int byte = (d * 128 + row * 2) ^ ((d & 7) << 4);
                    *reinterpret_cast<unsigned short*>(reinterpret_cast<char*>(a_lds) + byte) = f2bf(acc[rt][ct][r]);
                }
            }
        __syncthreads();
        const int bb = r0 >> 11;
        const int s0 = r0 & 2047;
        #pragma unroll
        for (int pq = 0; pq < 4; ++pq){
            const int d  = pq * 128 + (tid >> 2);
            const int sc = (tid & 3) * 16;
            const int base = d * 128 + sc * 2;
            const int sw = (d & 7) << 4;
            const bf8 x0 = *reinterpret_cast<const bf8*>(reinterpret_cast<const char*>(a_lds) + (base ^ sw));
            const bf8 x1 = *reinterpret_cast<const bf8*>(reinterpret_cast<const char*>(a_lds) + ((base + 16) ^ sw));
            unsigned short* dst = vt + (size_t)(bb * 512 + d) * SEQ + s0 + sc;
            *reinterpret_cast<bf8*>(dst)     = x0;
            *reinterpret_cast<bf8*>(dst + 8) = x1;
        }
        return;
    }

    const float* gamma = (m == 1) ? kg  : qg;
    const float* beta  = (m == 1) ? kbe : qbe;
    // q gets SCQ * log2(e): softmax runs in exp2 domain (v_exp_f32 is base-2)
    const float scale  = (m == 1) ? 1.0f : SCQ * LOG2E;
    unsigned short* outp = (m == 1) ? kbuf : qbuf;

    __syncthreads();
    #pragma unroll
    for (int rt = 0; rt < 4; ++rt){
        #pragma unroll
        for (int r = 0; r < 4; ++r){
            float s1 = 0.f, s2 = 0.f;
            #pragma unroll
            for (int ct = 0; ct < 4; ++ct){ const float v = acc[rt][ct][r]; s1 += v; s2 += v * v; }
            // 16-lane reduce via DPP (was 4x2 ds_bpermute shfl chains)
            s1 = dppadd<0xB1>(s1); s1 = dppadd<0x4E>(s1); s1 = dppadd<0x141>(s1); s1 = dppadd<0x140>(s1);
            s2 = dppadd<0xB1>(s2); s2 = dppadd<0x4E>(s2); s2 = dppadd<0x141>(s2); s2 = dppadd<0x140>(s2);
            if (lr == 0){
                const int row = 16 * rt + g * 4 + r;
                red1[row * 8 + wv] = s1;
                red2[row * 8 + wv] = s2;
            }
        }
    }
    __syncthreads();
    if (tid < 64){
        float S1 = 0.f, S2 = 0.f;
        #pragma unroll
        for (int w = 0; w < 8; ++w){ S1 += red1[tid * 8 + w]; S2 += red2[tid * 8 + w]; }
        const float mu = S1 * (1.0f / 512.0f);
        const float var = S2 * (1.0f / 512.0f) - mu * mu;
        stat_mu[tid] = mu;
        stat_rs[tid] = rsqrtf(var + 1e-5f);
    }
    __syncthreads();
    #pragma unroll
    for (int rt = 0; rt < 4; ++rt){
        #pragma unroll
        for (int r = 0; r < 4; ++r){
            const int row = 16 * rt + g * 4 + r;
            const float mu = stat_mu[row];
            const float rs = stat_rs[row];
            #pragma unroll
            for (int ct = 0; ct < 4; ++ct){
                const int d = nb + 16 * ct + lr;
                const float v = ((acc[rt][ct][r] - mu) * rs * gamma[d] + beta[d]) * scale;
                outp[(size_t)(r0 + row) * DIM + d] = f2bf(v);
            }
        }
    }
}

// ---------------- kernel 2: flash attention, KB=64 (round-9 structure) ----------------
// grid 256 = 8 batch * 32 p. Rows 0-31 = qt=p (light), rows 32-63 = qt=63-p.
// Iteration j: phase1 = {glds K(2j+2,2j+3), PV(j-1), V(j) loads, QK(j)};
// b1 = lgkm only; phase2 = softmax(j) (exp2 domain, DPP reduces, m/l in regs);
// b2 = vmcnt(8) (drains 8 K glds, 8 V loads stay in flight). K ring-4 (128 KB).
__global__ __launch_bounds__(512, 2) void attn(
    const unsigned short* __restrict__ qb, const unsigned short* __restrict__ kb,
    const unsigned short* __restrict__ vt, const float* __restrict__ qin,
    const float* __restrict__ g_o, const float* __restrict__ b_o,
    float* __restrict__ outp)
{
    __shared__ unsigned short k_lds[4 * 32 * DIM];   // 128 KB ring-4, swizzled content
    __shared__ float s_lds[64][68];                  // 17.4 KB: 64x64 S + pad
    __shared__ unsigned short p_lds[64 * 64];        // 8 KB: 128B rows, XOR swz
    __shared__ float l_lds[64], fac_lds[64];
    // epilogue reduction arrays alias s_lds (dead after last softmax)
    float* red1    = &s_lds[0][0];
    float* red2    = red1 + 512;
    float* stat_mu = red2 + 512;
    float* stat_rs = stat_mu + 64;

    const int tid = threadIdx.x;
    const int wv  = tid >> 6;
    const int l   = tid & 63;
    const int g   = l >> 4;
    const int lr  = l & 15;
    const int b   = blockIdx.x & 7;
    const int p   = blockIdx.x >> 3;      // 0..31
    const int q0a = 32 * p;               // rows 0..31  (light)
    const int q0b = 32 * (63 - p);        // rows 32..63 (heavy)
    const int n2  = (65 - p) >> 1;        // kv pairs (17..32)
    const int jL  = p >> 1;               // last pair with light rows active

    const int ct  = wv & 1;               // QK col tile (16 cols within 32-tile)
    const int rt_ = wv >> 1;              // QK row tile (16 rows), 0..3

    // Q fragments: rows 16*rt_+lr, full K=512 (qf[16] = 64 VGPR)
    bf8 qf[16];
    {
        const int row = 16 * rt_ + lr;
        const int qglob = (row < 32) ? (q0a + row) : (q0b + row - 32);
        const unsigned short* qr = qb + (size_t)(b * SEQ + qglob) * DIM + g * 8;
        #pragma unroll
        for (int ks = 0; ks < 16; ++ks)
            qf[ks] = *reinterpret_cast<const bf8*>(qr + ks * 32);
    }

    // K staging: glds, linear dest + inverse-swizzled source (rows 4wv..4wv+3)
    auto kglds = [&](int t){
        const int bo = (t & 3) * (32 * DIM);
        #pragma unroll
        for (int i = 0; i < 4; ++i){
            const int row = 4 * wv + i;
            glds16(kb + (size_t)(b * SEQ + t * 32 + row) * DIM + ((l * 8) ^ ((row & 7) * 8)),
                   k_lds + bo + row * DIM);
        }
    };

    kglds(0);
    kglds(1);

    // running softmax stats in REGISTERS (row = tid>>3 is thread-stable;
    // all 8 threads of a row keep identical copies)
    float m_reg = -__builtin_inff();
    float l_reg = 0.0f;

    f4 acc[4][4];
    #pragma unroll
    for (int rt = 0; rt < 4; ++rt)
        #pragma unroll
        for (int cv = 0; cv < 4; ++cv)
            acc[rt][cv] = (f4){0.f, 0.f, 0.f, 0.f};
    bf8 vst[8];   // [cv][ks]: V fragments for current 64-kv chunk

    // prologue drain: K(0), K(1), Q frags
    asm volatile("s_waitcnt vmcnt(0)" ::: "memory");
    __builtin_amdgcn_s_barrier();
    __builtin_amdgcn_sched_barrier(0);

    // PV helper: consumes p_lds/fac (pair jp) + vst (V of pair jp)
    auto do_pv = [&](int jp){
        const bool frozen = (jp > jL);
        __builtin_amdgcn_s_setprio(1);
        #pragma unroll
        for (int rt = 0; rt < 4; ++rt){
            if (rt < 2 && frozen) continue;    // light rows frozen
            float f[4];
            #pragma unroll
            for (int r = 0; r < 4; ++r) f[r] = fac_lds[16 * rt + 4 * g + r];
            #pragma unroll
            for (int cv = 0; cv < 4; ++cv)
                #pragma unroll
                for (int r = 0; r < 4; ++r)
                    acc[rt][cv][r] *= f[r];
            const int prow = 16 * rt + lr;
            const int sw = (prow & 7) << 4;
            const bf8 pa0 = *reinterpret_cast<const bf8*>(
                reinterpret_cast<const char*>(p_lds) + prow * 128 + ((g * 16) ^ sw));
            const bf8 pa1 = *reinterpret_cast<const bf8*>(
                reinterpret_cast<const char*>(p_lds) + prow * 128 + ((64 + g * 16) ^ sw));
            #pragma unroll
            for (int cv = 0; cv < 4; ++cv){
                acc[rt][cv] = __builtin_amdgcn_mfma_f32_16x16x32_bf16(pa0, vst[2 * cv],     acc[rt][cv], 0, 0, 0);
                acc[rt][cv] = __builtin_amdgcn_mfma_f32_16x16x32_bf16(pa1, vst[2 * cv + 1], acc[rt][cv], 0, 0, 0);
            }
        }
        __builtin_amdgcn_s_setprio(0);
    };

    for (int j = 0; j < n2; ++j){
        const int k0 = 64 * j;
        const int tp = 2 * j + 2;
        if (tp     < 2 * n2) kglds(tp);
        if (tp + 1 < 2 * n2) kglds(tp + 1);

        // ---- PV for previous pair (vst = V(j-1)) ----
        if (j > 0) do_pv(j - 1);

        // ---- V(j) loads: 64 kv cols (consumed next iter / final) ----
        #pragma unroll
        for (int cv = 0; cv < 4; ++cv)
            #pragma unroll
            for (int ks = 0; ks < 2; ++ks)
                vst[2 * cv + ks] = *reinterpret_cast<const bf8*>(
                    vt + (size_t)(b * DIM + 64 * wv + 16 * cv + lr) * SEQ + k0 + 32 * ks + g * 8);

        // ---- QK(j): wave (rt_, ct), two 32-col halves, full K=512 each ----
        if (rt_ >= 2 || j <= jL){
            const int krow  = 16 * ct + lr;
            const int rbase = krow * 1024;
            const int rx    = (krow & 7) << 4;
            __builtin_amdgcn_s_setprio(1);
            #pragma unroll
            for (int h = 0; h < 2; ++h){
                const char* kbuf = reinterpret_cast<const char*>(k_lds) + ((2 * j + h) & 3) * 32768;
                f4 sa[4];
                sa[0] = (f4){0.f,0.f,0.f,0.f}; sa[1] = (f4){0.f,0.f,0.f,0.f};
                sa[2] = (f4){0.f,0.f,0.f,0.f}; sa[3] = (f4){0.f,0.f,0.f,0.f};
                #pragma unroll
                for (int ks = 0; ks < 16; ++ks){
                    const bf8 bk = *reinterpret_cast<const bf8*>(
                        kbuf + rbase + ((ks * 64 + g * 16) ^ rx));
                    sa[ks & 3] = __builtin_amdgcn_mfma_f32_16x16x32_bf16(qf[ks], bk, sa[ks & 3], 0, 0, 0);
                }
                const f4 s = (sa[0] + sa[1]) + (sa[2] + sa[3]);
                const int srow = 16 * rt_ + 4 * g;
                #pragma unroll
                for (int r = 0; r < 4; ++r)
                    s_lds[srow + r][32 * h + 16 * ct + lr] = s[r];
            }
            __builtin_amdgcn_s_setprio(0);
        }
        // b1: S visible; NO vmem drain (K/V loads stay in flight)
        asm volatile("s_waitcnt lgkmcnt(0)" ::: "memory");
        __builtin_amdgcn_s_barrier();
        __builtin_amdgcn_sched_barrier(0);

        // ---- softmax: row = tid>>3, 8 cols/thread over 64 kv cols ----
        // exp2 domain (log2e folded into q); DPP reduces; m/l in registers.
        {
            const int row = tid >> 3;
            const int cp  = tid & 7;
            if (row >= 32 || j <= jL){
                const float4 x0 = *reinterpret_cast<const float4*>(&s_lds[row][8 * cp]);
                const float4 x1 = *reinterpret_cast<const float4*>(&s_lds[row][8 * cp + 4]);
                float av[8] = {x0.x, x0.y, x0.z, x0.w, x1.x, x1.y, x1.z, x1.w};
                const int qrow = (row < 32) ? (q0a + row) : (q0b + row - 32);
                const int kc = k0 + 8 * cp;
                #pragma unroll
                for (int jj = 0; jj < 8; ++jj)
                    if (kc + jj > qrow) av[jj] = -1e30f;
                float pm = fmaxf(fmaxf(fmaxf(av[0], av[1]), fmaxf(av[2], av[3])),
                                 fmaxf(fmaxf(av[4], av[5]), fmaxf(av[6], av[7])));
                pm = dppmax<0xB1>(pm); pm = dppmax<0x4E>(pm); pm = dppmax<0x141>(pm);
                const float mo = m_reg;
                const float mn = fmaxf(mo, pm);
                float e[8];
                #pragma unroll
                for (int jj = 0; jj < 8; ++jj) e[jj] = exp2fast(av[jj] - mn);
                float ts = ((e[0] + e[1]) + (e[2] + e[3])) + ((e[4] + e[5]) + (e[6] + e[7]));
                ts = dppadd<0xB1>(ts); ts = dppadd<0x4E>(ts); ts = dppadd<0x141>(ts);
                const float fc = exp2fast(mo - mn);
                m_reg = mn;
                l_reg = l_reg * fc + ts;
                if (cp == 0) fac_lds[row] = fc;
                uint4 pk;
                pk.x = (unsigned int)f2bf(e[0]) | ((unsigned int)f2bf(e[1]) << 16);
                pk.y = (unsigned int)f2bf(e[2]) | ((unsigned int)f2bf(e[3]) << 16);
                pk.z = (unsigned int)f2bf(e[4]) | ((unsigned int)f2bf(e[5]) << 16);
                pk.w = (unsigned int)f2bf(e[6]) | ((unsigned int)f2bf(e[7]) << 16);
                *reinterpret_cast<uint4*>(reinterpret_cast<char*>(p_lds) +
                    row * 128 + ((cp * 16) ^ ((row & 7) << 4))) = pk;
            }
        }
        // b2: P/fac visible AND prefetched K landed (8 glds drained; 8 V loads in flight)
        asm volatile("s_waitcnt vmcnt(8)" ::: "memory");
        asm volatile("s_waitcnt lgkmcnt(0)" ::: "memory");
        __builtin_amdgcn_s_barrier();
        __builtin_amdgcn_sched_barrier(0);
    }

    // publish register l to LDS for the epilogue's (different) thread mapping
    if ((tid & 7) == 0) l_lds[tid >> 3] = l_reg;

    // final PV (softmax/V of pair n2-1)
    asm volatile("s_waitcnt vmcnt(0)" ::: "memory");
    do_pv(n2 - 1);
    __syncthreads();   // l_lds visible to all

    // ---- finalize: /l, +residual, LN, store (64 rows) ----
    float li[4][4];
    #pragma unroll
    for (int rt = 0; rt < 4; ++rt)
        #pragma unroll
        for (int r = 0; r < 4; ++r)
            li[rt][r] = 1.0f / l_lds[16 * rt + 4 * g + r];
    #pragma unroll
    for (int rt = 0; rt < 4; ++rt){
        #pragma unroll
        for (int cv = 0; cv < 4; ++cv){
            #pragma unroll
            for (int r = 0; r < 4; ++r){
                const int row = 16 * rt + 4 * g + r;
                const int qglob = (row < 32) ? (q0a + row) : (q0b + row - 32);
                const int d = 64 * wv + 16 * cv + lr;
                acc[rt][cv][r] = acc[rt][cv][r] * li[rt][r]
                               + qin[(size_t)(b * SEQ + qglob) * DIM + d];
            }
        }
    }
    __syncthreads();   // s_lds reads fully done (aliased by red1/red2 below)
    #pragma unroll
    for (int rt = 0; rt < 4; ++rt){
        #pragma unroll
        for (int r = 0; r < 4; ++r){
            float s1 = 0.f, s2 = 0.f;
            #pragma unroll
            for (int cv = 0; cv < 4; ++cv){ const float v = acc[rt][cv][r]; s1 += v; s2 += v * v; }
            s1 = dppadd<0xB1>(s1); s1 = dppadd<0x4E>(s1); s1 = dppadd<0x141>(s1); s1 = dppadd<0x140>(s1);
            s2 = dppadd<0xB1>(s2); s2 = dppadd<0x4E>(s2); s2 = dppadd<0x141>(s2); s2 = dppadd<0x140>(s2);
            if (lr == 0){
                const int row = 16 * rt + 4 * g + r;
                red1[row * 8 + wv] = s1;
                red2[row * 8 + wv] = s2;
            }
        }
    }
    __syncthreads();
    if (tid < 64){
        float S1 = 0.f, S2 = 0.f;
        #pragma unroll
        for (int w = 0; w < 8; ++w){ S1 += red1[tid * 8 + w]; S2 += red2[tid * 8 + w]; }
        const float mu = S1 * (1.0f / 512.0f);
        const float var = S2 * (1.0f / 512.0f) - mu * mu;
        stat_mu[tid] = mu;
        stat_rs[tid] = rsqrtf(var + 1e-5f);
    }
    __syncthreads();
    #pragma unroll
    for (int rt = 0; rt < 4; ++rt){
        #pragma unroll
        for (int r = 0; r < 4; ++r){
            const int row = 16 * rt + 4 * g + r;
            const int qglob = (row < 32) ? (q0a + row) : (q0b + row - 32);
            const float mu = stat_mu[row];
            const float rs = stat_rs[row];
            #pragma unroll
            for (int cv = 0; cv < 4; ++cv){
                const int d = 64 * wv + 16 * cv + lr;
                outp[(size_t)(b * SEQ + qglob) * DIM + d] =
                    (acc[rt][cv][r] - mu) * rs * g_o[d] + b_o[d];
            }
        }
    }
}

extern "C" void kernel_launch(void* const* d_in, const int* in_sizes, int n_in,
                              void* d_out, int out_size, void* d_ws, size_t ws_size,
                              hipStream_t stream)
{
    (void)in_sizes; (void)n_in; (void)out_size; (void)ws_size;
    const float* vals = (const float*)d_in[0];
    const float* keys = (const float*)d_in[1];
    const float* ques = (const float*)d_in[2];
    const float* Wv   = (const float*)d_in[5];
    const float* Wk   = (const float*)d_in[6];
    const float* Wq   = (const float*)d_in[7];
    const float* ln_k_g = (const float*)d_in[8];
    const float* ln_k_b = (const float*)d_in[9];
    const float* ln_q_g = (const float*)d_in[10];
    const float* ln_q_b = (const float*)d_in[11];
    const float* ln_o_g = (const float*)d_in[12];
    const float* ln_o_b = (const float*)d_in[13];
    float* outp = (float*)d_out;

    char* ws = (char*)d_ws;
    unsigned short* qbuf = (unsigned short*)(ws);
    unsigned short* kbuf = (unsigned short*)(ws + (size_t)16 * 1024 * 1024);
    unsigned short* vt   = (unsigned short*)(ws + (size_t)32 * 1024 * 1024);
    unsigned short* Wt   = (unsigned short*)(ws + (size_t)48 * 1024 * 1024);

    prep_w<<<dim3(64, 3), 256, 0, stream>>>(Wv, Wk, Wq, Wt);

    gemm3<<<768, 512, 0, stream>>>(vals, keys, ques, Wt,
                                   ln_k_g, ln_k_b, ln_q_g, ln_q_b,
                                   vt, kbuf, qbuf);

    attn<<<256, 512, 0, stream>>>(qbuf, kbuf, vt, ques, ln_o_g, ln_o_b, outp);
}